// Round 9
// baseline (1116.932 us; speedup 1.0000x reference)
//
#include <hip/hip_runtime.h>
#include <hip/hip_bf16.h>
#include <stdint.h>

typedef unsigned short u16;
typedef short v8s __attribute__((ext_vector_type(8)));
typedef float v4f __attribute__((ext_vector_type(4)));
typedef uint32_t v2u __attribute__((ext_vector_type(2)));

#define DIM 192
#define NH 6
#define IMG 224
#define NWIN 28
#define NB 8
#define NWINDOWS (NB*NWIN*NWIN)
#define SCALE 0.17677669529663687f
#define AO_STR 200   // bf16 stride for attn_out tile (dword stride ≡4 mod 32: 2-way free)

// X-tile swizzle: bijective per token; (tok&7)^(tok>>3) separates same-(c,tcol)
// lanes across trow (token stride 192 u16 ≡ bank-0 aligned otherwise)
#define SWZ(tok) ((((tok) & 7) ^ ((tok) >> 3)) << 3)

__device__ __forceinline__ u16 f2bf(float f) {
    union { __hip_bfloat16 b; u16 u; } c; c.b = __float2bfloat16(f); return c.u;
}
__device__ __forceinline__ uint32_t pk2(float lo, float hi) {
    union { __hip_bfloat162 b; uint32_t u; } c;
    c.b = __float22bfloat162_rn(make_float2(lo, hi));
    return c.u;
}

// ---- prep: bf16 weights (SCALE folded into q rows), scaled bias, expanded bias table ----
__global__ void prep_kernel(const float* __restrict__ qkv_w,
                            const float* __restrict__ qkv_b,
                            const float* __restrict__ proj_w,
                            const float* __restrict__ rel_bias,
                            const int* __restrict__ rel_idx,
                            u16* __restrict__ qw, u16* __restrict__ pw,
                            float* __restrict__ qb2, float* __restrict__ biasT) {
    int i = blockIdx.x * 256 + threadIdx.x;
    if (i < 3*DIM*DIM) {
        float s = (i < DIM*DIM) ? SCALE : 1.f;
        qw[i] = f2bf(qkv_w[i] * s);
    }
    if (i < DIM*DIM) pw[i] = f2bf(proj_w[i]);
    if (i < 3*DIM)   qb2[i] = qkv_b[i] * (i < DIM ? SCALE : 1.f);
    if (i < NH*64*64) {
        int h   = i >> 12;          // biasT[h][query][key], key minor
        int qk2 = i & 4095;
        biasT[i] = rel_bias[rel_idx[qk2]*NH + h];
    }
}

// ---- fused window attention: one block per window, wave wv owns head wv ----
__global__ __launch_bounds__(384, 4) void winattn_kernel(
    const float* __restrict__ x,
    const float* __restrict__ proj_b,
    const u16* __restrict__ qw,
    const u16* __restrict__ pw,
    const float* __restrict__ qb2,
    const float* __restrict__ biasT,
    float* __restrict__ out)
{
    __shared__ __align__(16) u16 bufX[64 * DIM];     // 24576 B: X swizzled [64][192]
    __shared__ __align__(16) u16 bufO[64 * AO_STR];  // 25600 B: attn_out [64][200]   (total 50176 B)

    const int tid  = threadIdx.x;
    const int wv   = tid >> 6;
    const int lane = tid & 63;
    const int l15  = lane & 15;
    const int g    = lane >> 4;

    // XCD swizzle: dispatch i -> XCD i%8; each XCD gets one full image
    const int b  = blockIdx.x & 7;
    const int rm = blockIdx.x >> 3;
    const int wi = rm / NWIN;
    const int wj = rm % NWIN;

    // gather geometry: thread -> (4 tokens of one window row, channels c0+24*it)
    const int qq   = tid & 15;
    const int trow = qq >> 1;
    const int tcol = (qq & 1) * 4;
    const int t0   = trow*8 + tcol;
    const int c0   = tid >> 4;
    int ghh = wi*8 + trow + 4; if (ghh >= IMG) ghh -= IMG;   // roll(-4) folded in
    int gww = wj*8 + tcol + 4; if (gww >= IMG) gww -= IMG;   // 16B vector never straddles wrap
    const size_t pixoff = (size_t)ghh*IMG + gww;

    // ---------- phase 0: gather (float4) -> bufX swizzled [64][192] ----------
    const float* xb = x + (size_t)b * DIM*IMG*IMG;
    {
        v4f buf[8];
        #pragma unroll
        for (int it = 0; it < 8; ++it)
            buf[it] = *(const v4f*)(xb + (size_t)(c0 + it*24)*(IMG*IMG) + pixoff);
        #pragma unroll
        for (int it = 0; it < 8; ++it) {
            int c = c0 + it*24;
            #pragma unroll
            for (int i = 0; i < 4; ++i) {
                int tok = t0 + i;
                bufX[tok*DIM + (c ^ SWZ(tok))] = f2bf(buf[it][i]);
            }
        }
    }
    __syncthreads();   // B1: X published

    // ---------- phase 1a: V GEMM (normal orientation, r5-proven) ----------
    uint32_t vd[4][2][2];   // vd[mt][ntl][p] = V[16mt+4g+2p+{0,1}][ntl*16+l15]
    {
        v4f vacc[4][2];
        #pragma unroll
        for (int mt = 0; mt < 4; ++mt)
            #pragma unroll
            for (int ntl = 0; ntl < 2; ++ntl)
                vacc[mt][ntl] = (v4f){0.f,0.f,0.f,0.f};
        #pragma unroll
        for (int kk = 0; kk < 6; ++kk) {
            v8s xfr[4];
            #pragma unroll
            for (int mt = 0; mt < 4; ++mt) {
                int tok = mt*16 + l15;
                xfr[mt] = *(const v8s*)&bufX[tok*DIM + ((kk*32 + g*8) ^ SWZ(tok))];
            }
            #pragma unroll
            for (int ntl = 0; ntl < 2; ++ntl) {
                int o = 2*DIM + wv*32 + ntl*16 + l15;
                v8s wvf = *(const v8s*)(qw + (size_t)o*DIM + kk*32 + g*8);
                #pragma unroll
                for (int mt = 0; mt < 4; ++mt)
                    vacc[mt][ntl] = __builtin_amdgcn_mfma_f32_16x16x32_bf16(xfr[mt], wvf, vacc[mt][ntl], 0, 0, 0);
            }
        }
        #pragma unroll
        for (int ntl = 0; ntl < 2; ++ntl) {
            const float bv = qb2[2*DIM + wv*32 + ntl*16 + l15];
            #pragma unroll
            for (int mt = 0; mt < 4; ++mt) {
                vd[mt][ntl][0] = pk2(vacc[mt][ntl][0]+bv, vacc[mt][ntl][1]+bv);
                vd[mt][ntl][1] = pk2(vacc[mt][ntl][2]+bv, vacc[mt][ntl][3]+bv);
            }
        }
    }

    // ---------- phase 1b: Q^T GEMM (transposed; 32-AGPR accumulator) ----------
    // C layout: lane = token, regs = features (feat = ntl*16 + 4g + r)
    v8s qfr[4];
    {
        v4f qacc[2][4];
        #pragma unroll
        for (int ntl = 0; ntl < 2; ++ntl)
            #pragma unroll
            for (int qt = 0; qt < 4; ++qt)
                qacc[ntl][qt] = (v4f){0.f,0.f,0.f,0.f};
        #pragma unroll
        for (int kk = 0; kk < 6; ++kk) {
            v8s xfr[4];
            #pragma unroll
            for (int qt = 0; qt < 4; ++qt) {
                int tok = qt*16 + l15;
                xfr[qt] = *(const v8s*)&bufX[tok*DIM + ((kk*32 + g*8) ^ SWZ(tok))];
            }
            #pragma unroll
            for (int ntl = 0; ntl < 2; ++ntl) {
                v8s wq = *(const v8s*)(qw + (size_t)(wv*32 + ntl*16 + l15)*DIM + kk*32 + g*8);
                #pragma unroll
                for (int qt = 0; qt < 4; ++qt)
                    qacc[ntl][qt] = __builtin_amdgcn_mfma_f32_16x16x32_bf16(wq, xfr[qt], qacc[ntl][qt], 0, 0, 0);
            }
        }
        // bias along regs; pack into S-operand frags (sigma2 slot map, in-lane repack)
        v4f bqv[2];
        #pragma unroll
        for (int ntl = 0; ntl < 2; ++ntl)
            bqv[ntl] = *(const v4f*)&qb2[wv*32 + ntl*16 + 4*g];
        #pragma unroll
        for (int qt = 0; qt < 4; ++qt) {
            union { v8s v; uint32_t d[4]; } uq;
            uq.d[0] = pk2(qacc[0][qt][0]+bqv[0][0], qacc[0][qt][1]+bqv[0][1]);
            uq.d[1] = pk2(qacc[0][qt][2]+bqv[0][2], qacc[0][qt][3]+bqv[0][3]);
            uq.d[2] = pk2(qacc[1][qt][0]+bqv[1][0], qacc[1][qt][1]+bqv[1][1]);
            uq.d[3] = pk2(qacc[1][qt][2]+bqv[1][2], qacc[1][qt][3]+bqv[1][3]);
            qfr[qt] = uq.v;
        }
    }

    // ---------- phase 1c: K^T GEMM (same structure) ----------
    v8s kfr[4];
    {
        v4f kacc[2][4];
        #pragma unroll
        for (int ntl = 0; ntl < 2; ++ntl)
            #pragma unroll
            for (int qt = 0; qt < 4; ++qt)
                kacc[ntl][qt] = (v4f){0.f,0.f,0.f,0.f};
        #pragma unroll
        for (int kk = 0; kk < 6; ++kk) {
            v8s xfr[4];
            #pragma unroll
            for (int qt = 0; qt < 4; ++qt) {
                int tok = qt*16 + l15;
                xfr[qt] = *(const v8s*)&bufX[tok*DIM + ((kk*32 + g*8) ^ SWZ(tok))];
            }
            #pragma unroll
            for (int ntl = 0; ntl < 2; ++ntl) {
                v8s wk = *(const v8s*)(qw + (size_t)(DIM + wv*32 + ntl*16 + l15)*DIM + kk*32 + g*8);
                #pragma unroll
                for (int qt = 0; qt < 4; ++qt)
                    kacc[ntl][qt] = __builtin_amdgcn_mfma_f32_16x16x32_bf16(wk, xfr[qt], kacc[ntl][qt], 0, 0, 0);
            }
        }
        v4f bkv[2];
        #pragma unroll
        for (int ntl = 0; ntl < 2; ++ntl)
            bkv[ntl] = *(const v4f*)&qb2[DIM + wv*32 + ntl*16 + 4*g];
        #pragma unroll
        for (int qt = 0; qt < 4; ++qt) {
            union { v8s v; uint32_t d[4]; } uk;
            uk.d[0] = pk2(kacc[0][qt][0]+bkv[0][0], kacc[0][qt][1]+bkv[0][1]);
            uk.d[1] = pk2(kacc[0][qt][2]+bkv[0][2], kacc[0][qt][3]+bkv[0][3]);
            uk.d[2] = pk2(kacc[1][qt][0]+bkv[1][0], kacc[1][qt][1]+bkv[1][1]);
            uk.d[3] = pk2(kacc[1][qt][2]+bkv[1][2], kacc[1][qt][3]+bkv[1][3]);
            kfr[qt] = uk.v;
        }
    }

    // ---------- phase 2: attention (registers only; r5-proven) ----------
    // S^T = K Q^T : sacc[kt][qt][r] = S[key=16kt+4g+r][query=16qt+l15]
    v4f sacc[4][4];
    #pragma unroll
    for (int kt = 0; kt < 4; ++kt)
        #pragma unroll
        for (int qt = 0; qt < 4; ++qt)
            sacc[kt][qt] = __builtin_amdgcn_mfma_f32_16x16x32_bf16(kfr[kt], qfr[qt],
                                (v4f){0.f,0.f,0.f,0.f}, 0, 0, 0);

    const float* bt = biasT + wv*4096;
    #pragma unroll
    for (int qt = 0; qt < 4; ++qt) {
        #pragma unroll
        for (int kt = 0; kt < 4; ++kt) {
            v4f bb = *(const v4f*)&bt[(qt*16 + l15)*64 + kt*16 + 4*g];
            sacc[kt][qt] += bb;
        }
        float mx = sacc[0][qt][0];
        #pragma unroll
        for (int kt = 0; kt < 4; ++kt)
            #pragma unroll
            for (int r = 0; r < 4; ++r) mx = fmaxf(mx, sacc[kt][qt][r]);
        mx = fmaxf(mx, __shfl_xor(mx, 16));
        mx = fmaxf(mx, __shfl_xor(mx, 32));
        float sum = 0.f;
        #pragma unroll
        for (int kt = 0; kt < 4; ++kt)
            #pragma unroll
            for (int r = 0; r < 4; ++r) {
                float e = __expf(sacc[kt][qt][r] - mx);
                sacc[kt][qt][r] = e; sum += e;
            }
        sum += __shfl_xor(sum, 16);
        sum += __shfl_xor(sum, 32);
        float inv = 1.f / sum;
        #pragma unroll
        for (int kt = 0; kt < 4; ++kt)
            #pragma unroll
            for (int r = 0; r < 4; ++r) sacc[kt][qt][r] *= inv;
    }

    // O^T = V^T P^T via register repacks; slot (g,j) <-> key 16*(2kk+(j>>2))+4g+(j&3)
    v4f oT[2][4];   // [ntl][qt]: O[query=16qt+l15][d=16ntl+4g+r]
    #pragma unroll
    for (int ntl = 0; ntl < 2; ++ntl)
        #pragma unroll
        for (int qt = 0; qt < 4; ++qt)
            oT[ntl][qt] = (v4f){0.f,0.f,0.f,0.f};
    #pragma unroll
    for (int kk = 0; kk < 2; ++kk) {
        v8s vfr[2];
        #pragma unroll
        for (int ntl = 0; ntl < 2; ++ntl) {
            union { v8s v; uint32_t d[4]; } uu;
            uu.d[0] = vd[2*kk  ][ntl][0]; uu.d[1] = vd[2*kk  ][ntl][1];
            uu.d[2] = vd[2*kk+1][ntl][0]; uu.d[3] = vd[2*kk+1][ntl][1];
            vfr[ntl] = uu.v;
        }
        #pragma unroll
        for (int qt = 0; qt < 4; ++qt) {
            union { v8s v; uint32_t d[4]; } p;
            p.d[0] = pk2(sacc[2*kk  ][qt][0], sacc[2*kk  ][qt][1]);
            p.d[1] = pk2(sacc[2*kk  ][qt][2], sacc[2*kk  ][qt][3]);
            p.d[2] = pk2(sacc[2*kk+1][qt][0], sacc[2*kk+1][qt][1]);
            p.d[3] = pk2(sacc[2*kk+1][qt][2], sacc[2*kk+1][qt][3]);
            #pragma unroll
            for (int ntl = 0; ntl < 2; ++ntl)
                oT[ntl][qt] = __builtin_amdgcn_mfma_f32_16x16x32_bf16(vfr[ntl], p.v, oT[ntl][qt], 0, 0, 0);
        }
    }

    // attn_out -> bufO [64][AO_STR], b64 stores
    #pragma unroll
    for (int qt = 0; qt < 4; ++qt)
        #pragma unroll
        for (int ntl = 0; ntl < 2; ++ntl) {
            v2u o;
            o.x = pk2(oT[ntl][qt][0], oT[ntl][qt][1]);
            o.y = pk2(oT[ntl][qt][2], oT[ntl][qt][3]);
            *(v2u*)&bufO[(qt*16 + l15)*AO_STR + wv*32 + ntl*16 + 4*g] = o;
        }
    __syncthreads();   // B2: AO complete

    // ---------- phase 3: transposed proj GEMM + direct register scatter (r5-proven) ----------
    v4f pacc[2][4];    // [ntl][qt]: P[out=wv*32+16ntl+4g+r][tok=16qt+l15]
    #pragma unroll
    for (int ntl = 0; ntl < 2; ++ntl)
        #pragma unroll
        for (int qt = 0; qt < 4; ++qt)
            pacc[ntl][qt] = (v4f){0.f,0.f,0.f,0.f};
    #pragma unroll
    for (int kk = 0; kk < 6; ++kk) {
        v8s aofr[4];
        #pragma unroll
        for (int qt = 0; qt < 4; ++qt)
            aofr[qt] = *(const v8s*)&bufO[(qt*16 + l15)*AO_STR + kk*32 + g*8];
        #pragma unroll
        for (int ntl = 0; ntl < 2; ++ntl) {
            v8s pwfr = *(const v8s*)(pw + (size_t)(wv*32 + ntl*16 + l15)*DIM + kk*32 + g*8);
            #pragma unroll
            for (int qt = 0; qt < 4; ++qt)
                pacc[ntl][qt] = __builtin_amdgcn_mfma_f32_16x16x32_bf16(pwfr, aofr[qt], pacc[ntl][qt], 0, 0, 0);
        }
    }
    float pb[2][4];
    #pragma unroll
    for (int ntl = 0; ntl < 2; ++ntl) {
        v4f pbv = *(const v4f*)&proj_b[wv*32 + ntl*16 + 4*g];
        #pragma unroll
        for (int r = 0; r < 4; ++r) pb[ntl][r] = pbv[r];
    }

    float* ob = out + (size_t)b * DIM*IMG*IMG;
    #pragma unroll
    for (int qt = 0; qt < 4; ++qt) {
        const int strow = 2*qt + (l15 >> 3);
        const int stcol = l15 & 7;
        int hh = wi*8 + strow + 4; if (hh >= IMG) hh -= IMG;
        int ww = wj*8 + stcol + 4; if (ww >= IMG) ww -= IMG;
        const size_t pix = (size_t)hh*IMG + ww;
        #pragma unroll
        for (int ntl = 0; ntl < 2; ++ntl)
            #pragma unroll
            for (int r = 0; r < 4; ++r) {
                const int c = wv*32 + ntl*16 + 4*g + r;
                ob[(size_t)c*(IMG*IMG) + pix] = pacc[ntl][qt][r] + pb[ntl][r];
            }
    }
}

extern "C" void kernel_launch(void* const* d_in, const int* in_sizes, int n_in,
                              void* d_out, int out_size, void* d_ws, size_t ws_size,
                              hipStream_t stream) {
    const float* x        = (const float*)d_in[0];
    const float* qkv_w    = (const float*)d_in[1];
    const float* qkv_b    = (const float*)d_in[2];
    const float* proj_w   = (const float*)d_in[3];
    const float* proj_b   = (const float*)d_in[4];
    const float* rel_bias = (const float*)d_in[5];
    const int*   rel_idx  = (const int*)d_in[6];

    u16*   qw_bf  = (u16*)d_ws;                         // 221184 B
    u16*   pw_bf  = (u16*)((char*)d_ws + 221184);       //  73728 B
    float* qb2    = (float*)((char*)d_ws + 294912);     //   2304 B
    float* biasT  = (float*)((char*)d_ws + 297216);     //  98304 B
    float* out    = (float*)d_out;

    hipLaunchKernelGGL(prep_kernel, dim3(432), dim3(256), 0, stream,
                       qkv_w, qkv_b, proj_w, rel_bias, rel_idx, qw_bf, pw_bf, qb2, biasT);
    hipLaunchKernelGGL(winattn_kernel, dim3(NWINDOWS), dim3(384), 0, stream,
                       x, proj_b, qw_bf, pw_bf, qb2, biasT, out);
}

// Round 10
// 720.054 us; speedup vs baseline: 1.5512x; 1.5512x over previous
//
#include <hip/hip_runtime.h>
#include <hip/hip_bf16.h>
#include <stdint.h>

typedef unsigned short u16;
typedef short v8s __attribute__((ext_vector_type(8)));
typedef float v4f __attribute__((ext_vector_type(4)));
typedef uint32_t v2u __attribute__((ext_vector_type(2)));

#define DIM 192
#define NH 6
#define IMG 224
#define NWIN 28
#define NB 8
#define NWINDOWS (NB*NWIN*NWIN)
#define SCALE 0.17677669529663687f
#define AO_STR 200   // bf16 stride for attn_out tile (dword stride ≡4 mod 32: 2-way free)

// X-tile swizzle (r9-proven): bijective per token, halves gather-store conflicts
#define SWZ(tok) ((((tok) & 7) ^ ((tok) >> 3)) << 3)

__device__ __forceinline__ u16 f2bf(float f) {
    union { __hip_bfloat16 b; u16 u; } c; c.b = __float2bfloat16(f); return c.u;
}
__device__ __forceinline__ uint32_t pk2(float lo, float hi) {
    union { __hip_bfloat162 b; uint32_t u; } c;
    c.b = __float22bfloat162_rn(make_float2(lo, hi));
    return c.u;
}

// ---- prep: bf16 weights (SCALE folded into q rows), scaled bias, expanded bias table ----
__global__ void prep_kernel(const float* __restrict__ qkv_w,
                            const float* __restrict__ qkv_b,
                            const float* __restrict__ proj_w,
                            const float* __restrict__ rel_bias,
                            const int* __restrict__ rel_idx,
                            u16* __restrict__ qw, u16* __restrict__ pw,
                            float* __restrict__ qb2, float* __restrict__ biasT) {
    int i = blockIdx.x * 256 + threadIdx.x;
    if (i < 3*DIM*DIM) {
        float s = (i < DIM*DIM) ? SCALE : 1.f;
        qw[i] = f2bf(qkv_w[i] * s);
    }
    if (i < DIM*DIM) pw[i] = f2bf(proj_w[i]);
    if (i < 3*DIM)   qb2[i] = qkv_b[i] * (i < DIM ? SCALE : 1.f);
    if (i < NH*64*64) {
        int h   = i >> 12;          // biasT[h][query][key], key minor
        int qk2 = i & 4095;
        biasT[i] = rel_bias[rel_idx[qk2]*NH + h];
    }
}

// ---- fused window attention: one block per window, 12 waves, wave (h,u) = head h / query-half u ----
__global__ __launch_bounds__(768, 3) void winattn_kernel(
    const float* __restrict__ x,
    const float* __restrict__ proj_b,
    const u16* __restrict__ qw,
    const u16* __restrict__ pw,
    const float* __restrict__ qb2,
    const float* __restrict__ biasT,
    float* __restrict__ out)
{
    __shared__ __align__(16) u16 bufX[64 * DIM];     // 24576 B: X swizzled [64][192]
    __shared__ __align__(16) u16 bufO[64 * AO_STR];  // 25600 B: attn_out [64][200]   (total 50176 B)

    const int tid  = threadIdx.x;
    const int wv   = tid >> 6;          // 0..11
    const int h    = wv >> 1;           // head 0..5
    const int u    = wv & 1;            // query-half 0..1
    const int lane = tid & 63;
    const int l15  = lane & 15;
    const int g    = lane >> 4;

    // XCD swizzle: dispatch i -> XCD i%8; each XCD gets one full image
    const int b  = blockIdx.x & 7;
    const int rm = blockIdx.x >> 3;
    const int wi = rm / NWIN;
    const int wj = rm % NWIN;

    // gather geometry: thread -> (4 tokens of one window row, channels c0+48*it)
    const int qq   = tid & 15;
    const int trow = qq >> 1;
    const int tcol = (qq & 1) * 4;
    const int t0   = trow*8 + tcol;
    const int c0   = tid >> 4;          // 0..47
    int ghh = wi*8 + trow + 4; if (ghh >= IMG) ghh -= IMG;   // roll(-4) folded in
    int gww = wj*8 + tcol + 4; if (gww >= IMG) gww -= IMG;   // 16B vector never straddles wrap
    const size_t pixoff = (size_t)ghh*IMG + gww;

    // ---------- phase 0: gather (float4) -> bufX swizzled [64][192] ----------
    const float* xb = x + (size_t)b * DIM*IMG*IMG;
    {
        v4f buf[4];
        #pragma unroll
        for (int it = 0; it < 4; ++it)
            buf[it] = *(const v4f*)(xb + (size_t)(c0 + it*48)*(IMG*IMG) + pixoff);
        #pragma unroll
        for (int it = 0; it < 4; ++it) {
            int c = c0 + it*48;
            #pragma unroll
            for (int i = 0; i < 4; ++i) {
                int tok = t0 + i;
                bufX[tok*DIM + (c ^ SWZ(tok))] = f2bf(buf[it][i]);
            }
        }
    }
    __syncthreads();   // B1: X published

    // ---------- phase 1a: V GEMM, all 64 tokens (normal orientation, r5-proven) ----------
    uint32_t vd[4][2][2];   // vd[mt][ntl][p] = V[16mt+4g+2p+{0,1}][ntl*16+l15]
    {
        v4f vacc[4][2];
        #pragma unroll
        for (int mt = 0; mt < 4; ++mt)
            #pragma unroll
            for (int ntl = 0; ntl < 2; ++ntl)
                vacc[mt][ntl] = (v4f){0.f,0.f,0.f,0.f};
        #pragma unroll
        for (int kk = 0; kk < 6; ++kk) {
            v8s xfr[4];
            #pragma unroll
            for (int mt = 0; mt < 4; ++mt) {
                int tok = mt*16 + l15;
                xfr[mt] = *(const v8s*)&bufX[tok*DIM + ((kk*32 + g*8) ^ SWZ(tok))];
            }
            #pragma unroll
            for (int ntl = 0; ntl < 2; ++ntl) {
                int o = 2*DIM + h*32 + ntl*16 + l15;
                v8s wvf = *(const v8s*)(qw + (size_t)o*DIM + kk*32 + g*8);
                #pragma unroll
                for (int mt = 0; mt < 4; ++mt)
                    vacc[mt][ntl] = __builtin_amdgcn_mfma_f32_16x16x32_bf16(xfr[mt], wvf, vacc[mt][ntl], 0, 0, 0);
            }
        }
        #pragma unroll
        for (int ntl = 0; ntl < 2; ++ntl) {
            const float bv = qb2[2*DIM + h*32 + ntl*16 + l15];
            #pragma unroll
            for (int mt = 0; mt < 4; ++mt) {
                vd[mt][ntl][0] = pk2(vacc[mt][ntl][0]+bv, vacc[mt][ntl][1]+bv);
                vd[mt][ntl][1] = pk2(vacc[mt][ntl][2]+bv, vacc[mt][ntl][3]+bv);
            }
        }
    }

    // ---------- phase 1b: Q^T GEMM, this wave's query-half only ----------
    v8s qfr[2];
    {
        v4f qacc[2][2];   // [ntl][qtl]
        #pragma unroll
        for (int ntl = 0; ntl < 2; ++ntl)
            #pragma unroll
            for (int qtl = 0; qtl < 2; ++qtl)
                qacc[ntl][qtl] = (v4f){0.f,0.f,0.f,0.f};
        #pragma unroll
        for (int kk = 0; kk < 6; ++kk) {
            v8s xfr[2];
            #pragma unroll
            for (int qtl = 0; qtl < 2; ++qtl) {
                int tok = (2*u + qtl)*16 + l15;
                xfr[qtl] = *(const v8s*)&bufX[tok*DIM + ((kk*32 + g*8) ^ SWZ(tok))];
            }
            #pragma unroll
            for (int ntl = 0; ntl < 2; ++ntl) {
                v8s wq = *(const v8s*)(qw + (size_t)(h*32 + ntl*16 + l15)*DIM + kk*32 + g*8);
                #pragma unroll
                for (int qtl = 0; qtl < 2; ++qtl)
                    qacc[ntl][qtl] = __builtin_amdgcn_mfma_f32_16x16x32_bf16(wq, xfr[qtl], qacc[ntl][qtl], 0, 0, 0);
            }
        }
        v4f bqv[2];
        #pragma unroll
        for (int ntl = 0; ntl < 2; ++ntl)
            bqv[ntl] = *(const v4f*)&qb2[h*32 + ntl*16 + 4*g];
        #pragma unroll
        for (int qtl = 0; qtl < 2; ++qtl) {
            union { v8s v; uint32_t d[4]; } uq;
            uq.d[0] = pk2(qacc[0][qtl][0]+bqv[0][0], qacc[0][qtl][1]+bqv[0][1]);
            uq.d[1] = pk2(qacc[0][qtl][2]+bqv[0][2], qacc[0][qtl][3]+bqv[0][3]);
            uq.d[2] = pk2(qacc[1][qtl][0]+bqv[1][0], qacc[1][qtl][1]+bqv[1][1]);
            uq.d[3] = pk2(qacc[1][qtl][2]+bqv[1][2], qacc[1][qtl][3]+bqv[1][3]);
            qfr[qtl] = uq.v;
        }
    }

    // ---------- phase 1c: K^T GEMM, all keys ----------
    v8s kfr[4];
    {
        v4f kacc[2][4];   // [ntl][kt]
        #pragma unroll
        for (int ntl = 0; ntl < 2; ++ntl)
            #pragma unroll
            for (int kt = 0; kt < 4; ++kt)
                kacc[ntl][kt] = (v4f){0.f,0.f,0.f,0.f};
        #pragma unroll
        for (int kk = 0; kk < 6; ++kk) {
            v8s xfr[4];
            #pragma unroll
            for (int kt = 0; kt < 4; ++kt) {
                int tok = kt*16 + l15;
                xfr[kt] = *(const v8s*)&bufX[tok*DIM + ((kk*32 + g*8) ^ SWZ(tok))];
            }
            #pragma unroll
            for (int ntl = 0; ntl < 2; ++ntl) {
                v8s wk = *(const v8s*)(qw + (size_t)(DIM + h*32 + ntl*16 + l15)*DIM + kk*32 + g*8);
                #pragma unroll
                for (int kt = 0; kt < 4; ++kt)
                    kacc[ntl][kt] = __builtin_amdgcn_mfma_f32_16x16x32_bf16(wk, xfr[kt], kacc[ntl][kt], 0, 0, 0);
            }
        }
        v4f bkv[2];
        #pragma unroll
        for (int ntl = 0; ntl < 2; ++ntl)
            bkv[ntl] = *(const v4f*)&qb2[DIM + h*32 + ntl*16 + 4*g];
        #pragma unroll
        for (int kt = 0; kt < 4; ++kt) {
            union { v8s v; uint32_t d[4]; } uk;
            uk.d[0] = pk2(kacc[0][kt][0]+bkv[0][0], kacc[0][kt][1]+bkv[0][1]);
            uk.d[1] = pk2(kacc[0][kt][2]+bkv[0][2], kacc[0][kt][3]+bkv[0][3]);
            uk.d[2] = pk2(kacc[1][kt][0]+bkv[1][0], kacc[1][kt][1]+bkv[1][1]);
            uk.d[3] = pk2(kacc[1][kt][2]+bkv[1][2], kacc[1][kt][3]+bkv[1][3]);
            kfr[kt] = uk.v;
        }
    }

    // ---------- phase 2: attention (registers only; r5-proven math) ----------
    // S^T = K Q^T : sacc[kt][qtl][r] = S[key=16kt+4g+r][query=16*(2u+qtl)+l15]
    v4f sacc[4][2];
    #pragma unroll
    for (int kt = 0; kt < 4; ++kt)
        #pragma unroll
        for (int qtl = 0; qtl < 2; ++qtl)
            sacc[kt][qtl] = __builtin_amdgcn_mfma_f32_16x16x32_bf16(kfr[kt], qfr[qtl],
                                (v4f){0.f,0.f,0.f,0.f}, 0, 0, 0);

    const float* bt = biasT + h*4096;
    #pragma unroll
    for (int qtl = 0; qtl < 2; ++qtl) {
        const int qrow = (2*u + qtl)*16 + l15;
        #pragma unroll
        for (int kt = 0; kt < 4; ++kt) {
            v4f bb = *(const v4f*)&bt[qrow*64 + kt*16 + 4*g];
            sacc[kt][qtl] += bb;
        }
        float mx = sacc[0][qtl][0];
        #pragma unroll
        for (int kt = 0; kt < 4; ++kt)
            #pragma unroll
            for (int r = 0; r < 4; ++r) mx = fmaxf(mx, sacc[kt][qtl][r]);
        mx = fmaxf(mx, __shfl_xor(mx, 16));
        mx = fmaxf(mx, __shfl_xor(mx, 32));
        float sum = 0.f;
        #pragma unroll
        for (int kt = 0; kt < 4; ++kt)
            #pragma unroll
            for (int r = 0; r < 4; ++r) {
                float e = __expf(sacc[kt][qtl][r] - mx);
                sacc[kt][qtl][r] = e; sum += e;
            }
        sum += __shfl_xor(sum, 16);
        sum += __shfl_xor(sum, 32);
        float inv = 1.f / sum;
        #pragma unroll
        for (int kt = 0; kt < 4; ++kt)
            #pragma unroll
            for (int r = 0; r < 4; ++r) sacc[kt][qtl][r] *= inv;
    }

    // O^T = V^T P^T via register repacks; slot (g,j) <-> key 16*(2kk+(j>>2))+4g+(j&3)
    v4f oT[2][2];   // [ntl][qtl]: O[query][d=16ntl+4g+r]
    #pragma unroll
    for (int ntl = 0; ntl < 2; ++ntl)
        #pragma unroll
        for (int qtl = 0; qtl < 2; ++qtl)
            oT[ntl][qtl] = (v4f){0.f,0.f,0.f,0.f};
    #pragma unroll
    for (int kk = 0; kk < 2; ++kk) {
        v8s vfr[2];
        #pragma unroll
        for (int ntl = 0; ntl < 2; ++ntl) {
            union { v8s v; uint32_t d[4]; } uu;
            uu.d[0] = vd[2*kk  ][ntl][0]; uu.d[1] = vd[2*kk  ][ntl][1];
            uu.d[2] = vd[2*kk+1][ntl][0]; uu.d[3] = vd[2*kk+1][ntl][1];
            vfr[ntl] = uu.v;
        }
        #pragma unroll
        for (int qtl = 0; qtl < 2; ++qtl) {
            union { v8s v; uint32_t d[4]; } p;
            p.d[0] = pk2(sacc[2*kk  ][qtl][0], sacc[2*kk  ][qtl][1]);
            p.d[1] = pk2(sacc[2*kk  ][qtl][2], sacc[2*kk  ][qtl][3]);
            p.d[2] = pk2(sacc[2*kk+1][qtl][0], sacc[2*kk+1][qtl][1]);
            p.d[3] = pk2(sacc[2*kk+1][qtl][2], sacc[2*kk+1][qtl][3]);
            #pragma unroll
            for (int ntl = 0; ntl < 2; ++ntl)
                oT[ntl][qtl] = __builtin_amdgcn_mfma_f32_16x16x32_bf16(vfr[ntl], p.v, oT[ntl][qtl], 0, 0, 0);
        }
    }

    // attn_out -> bufO [64][AO_STR], b64 stores (this wave's query rows, head cols)
    #pragma unroll
    for (int qtl = 0; qtl < 2; ++qtl)
        #pragma unroll
        for (int ntl = 0; ntl < 2; ++ntl) {
            v2u o;
            o.x = pk2(oT[ntl][qtl][0], oT[ntl][qtl][1]);
            o.y = pk2(oT[ntl][qtl][2], oT[ntl][qtl][3]);
            *(v2u*)&bufO[((2*u + qtl)*16 + l15)*AO_STR + h*32 + ntl*16 + 4*g] = o;
        }
    __syncthreads();   // B2: AO complete

    // ---------- phase 3: transposed proj GEMM + direct register scatter ----------
    v4f pacc[2][2];    // [ntl][qtl]: P[out=h*32+16ntl+4g+r][tok]
    #pragma unroll
    for (int ntl = 0; ntl < 2; ++ntl)
        #pragma unroll
        for (int qtl = 0; qtl < 2; ++qtl)
            pacc[ntl][qtl] = (v4f){0.f,0.f,0.f,0.f};
    #pragma unroll
    for (int kk = 0; kk < 6; ++kk) {
        v8s aofr[2];
        #pragma unroll
        for (int qtl = 0; qtl < 2; ++qtl)
            aofr[qtl] = *(const v8s*)&bufO[((2*u + qtl)*16 + l15)*AO_STR + kk*32 + g*8];
        #pragma unroll
        for (int ntl = 0; ntl < 2; ++ntl) {
            v8s pwfr = *(const v8s*)(pw + (size_t)(h*32 + ntl*16 + l15)*DIM + kk*32 + g*8);
            #pragma unroll
            for (int qtl = 0; qtl < 2; ++qtl)
                pacc[ntl][qtl] = __builtin_amdgcn_mfma_f32_16x16x32_bf16(pwfr, aofr[qtl], pacc[ntl][qtl], 0, 0, 0);
        }
    }
    float pb[2][4];
    #pragma unroll
    for (int ntl = 0; ntl < 2; ++ntl) {
        v4f pbv = *(const v4f*)&proj_b[h*32 + ntl*16 + 4*g];
        #pragma unroll
        for (int r = 0; r < 4; ++r) pb[ntl][r] = pbv[r];
    }

    float* ob = out + (size_t)b * DIM*IMG*IMG;
    #pragma unroll
    for (int qtl = 0; qtl < 2; ++qtl) {
        const int qt = 2*u + qtl;
        const int strow = 2*qt + (l15 >> 3);
        const int stcol = l15 & 7;
        int hh = wi*8 + strow + 4; if (hh >= IMG) hh -= IMG;
        int ww = wj*8 + stcol + 4; if (ww >= IMG) ww -= IMG;
        const size_t pix = (size_t)hh*IMG + ww;
        #pragma unroll
        for (int ntl = 0; ntl < 2; ++ntl)
            #pragma unroll
            for (int r = 0; r < 4; ++r) {
                const int c = h*32 + ntl*16 + 4*g + r;
                ob[(size_t)c*(IMG*IMG) + pix] = pacc[ntl][qtl][r] + pb[ntl][r];
            }
    }
}

extern "C" void kernel_launch(void* const* d_in, const int* in_sizes, int n_in,
                              void* d_out, int out_size, void* d_ws, size_t ws_size,
                              hipStream_t stream) {
    const float* x        = (const float*)d_in[0];
    const float* qkv_w    = (const float*)d_in[1];
    const float* qkv_b    = (const float*)d_in[2];
    const float* proj_w   = (const float*)d_in[3];
    const float* proj_b   = (const float*)d_in[4];
    const float* rel_bias = (const float*)d_in[5];
    const int*   rel_idx  = (const int*)d_in[6];

    u16*   qw_bf  = (u16*)d_ws;                         // 221184 B
    u16*   pw_bf  = (u16*)((char*)d_ws + 221184);       //  73728 B
    float* qb2    = (float*)((char*)d_ws + 294912);     //   2304 B
    float* biasT  = (float*)((char*)d_ws + 297216);     //  98304 B
    float* out    = (float*)d_out;

    hipLaunchKernelGGL(prep_kernel, dim3(432), dim3(256), 0, stream,
                       qkv_w, qkv_b, proj_w, rel_bias, rel_idx, qw_bf, pw_bf, qb2, biasT);
    hipLaunchKernelGGL(winattn_kernel, dim3(NWINDOWS), dim3(768), 0, stream,
                       x, proj_b, qw_bf, pw_bf, qb2, biasT, out);
}

// Round 11
// 639.963 us; speedup vs baseline: 1.7453x; 1.1251x over previous
//
#include <hip/hip_runtime.h>
#include <hip/hip_bf16.h>
#include <stdint.h>

typedef unsigned short u16;
typedef short v8s __attribute__((ext_vector_type(8)));
typedef float v4f __attribute__((ext_vector_type(4)));
typedef uint32_t v2u __attribute__((ext_vector_type(2)));

#define DIM 192
#define NH 6
#define IMG 224
#define NWIN 28
#define NB 8
#define NWINDOWS (NB*NWIN*NWIN)
#define SCALE 0.17677669529663687f
#define AO_STR 200   // bf16 stride for attn_out tile (dword stride ≡4 mod 32: 2-way free)

// X-tile swizzle (r9-proven): bijective per token, halves gather-store conflicts
#define SWZ(tok) ((((tok) & 7) ^ ((tok) >> 3)) << 3)

__device__ __forceinline__ u16 f2bf(float f) {
    union { __hip_bfloat16 b; u16 u; } c; c.b = __float2bfloat16(f); return c.u;
}
__device__ __forceinline__ uint32_t pk2(float lo, float hi) {
    union { __hip_bfloat162 b; uint32_t u; } c;
    c.b = __float22bfloat162_rn(make_float2(lo, hi));
    return c.u;
}

// ---- prep: bf16 weights (SCALE folded into q rows), scaled bias, expanded bias table ----
__global__ void prep_kernel(const float* __restrict__ qkv_w,
                            const float* __restrict__ qkv_b,
                            const float* __restrict__ proj_w,
                            const float* __restrict__ rel_bias,
                            const int* __restrict__ rel_idx,
                            u16* __restrict__ qw, u16* __restrict__ pw,
                            float* __restrict__ qb2, float* __restrict__ biasT) {
    int i = blockIdx.x * 256 + threadIdx.x;
    if (i < 3*DIM*DIM) {
        float s = (i < DIM*DIM) ? SCALE : 1.f;
        qw[i] = f2bf(qkv_w[i] * s);
    }
    if (i < DIM*DIM) pw[i] = f2bf(proj_w[i]);
    if (i < 3*DIM)   qb2[i] = qkv_b[i] * (i < DIM ? SCALE : 1.f);
    if (i < NH*64*64) {
        int h   = i >> 12;          // biasT[h][query][key], key minor
        int qk2 = i & 4095;
        biasT[i] = rel_bias[rel_idx[qk2]*NH + h];
    }
}

// ---- fused window attention: one block per window, wave wv owns head wv ----
__global__ __launch_bounds__(384, 3) void winattn_kernel(
    const float* __restrict__ x,
    const float* __restrict__ proj_b,
    const u16* __restrict__ qw,
    const u16* __restrict__ pw,
    const float* __restrict__ qb2,
    const float* __restrict__ biasT,
    float* __restrict__ out)
{
    __shared__ __align__(16) u16 bufX[64 * DIM];     // 24576 B: X swizzled [64][192]
    __shared__ __align__(16) u16 bufO[64 * AO_STR];  // 25600 B: attn_out [64][200]   (total 50176 B)

    const int tid  = threadIdx.x;
    const int wv   = tid >> 6;
    const int lane = tid & 63;
    const int l15  = lane & 15;
    const int g    = lane >> 4;

    // XCD swizzle: dispatch i -> XCD i%8; each XCD gets one full image
    const int b  = blockIdx.x & 7;
    const int rm = blockIdx.x >> 3;
    const int wi = rm / NWIN;
    const int wj = rm % NWIN;

    // gather geometry: thread -> (4 tokens of one window row, channels c0+24*it)
    const int qq   = tid & 15;
    const int trow = qq >> 1;
    const int tcol = (qq & 1) * 4;
    const int t0   = trow*8 + tcol;
    const int c0   = tid >> 4;
    int ghh = wi*8 + trow + 4; if (ghh >= IMG) ghh -= IMG;   // roll(-4) folded in
    int gww = wj*8 + tcol + 4; if (gww >= IMG) gww -= IMG;   // 16B vector never straddles wrap
    const size_t pixoff = (size_t)ghh*IMG + gww;

    // ---------- phase 0: gather (float4) -> bufX swizzled [64][192] ----------
    const float* xb = x + (size_t)b * DIM*IMG*IMG;
    {
        v4f buf[8];
        #pragma unroll
        for (int it = 0; it < 8; ++it)
            buf[it] = *(const v4f*)(xb + (size_t)(c0 + it*24)*(IMG*IMG) + pixoff);
        #pragma unroll
        for (int it = 0; it < 8; ++it) {
            int c = c0 + it*24;
            #pragma unroll
            for (int i = 0; i < 4; ++i) {
                int tok = t0 + i;
                bufX[tok*DIM + (c ^ SWZ(tok))] = f2bf(buf[it][i]);
            }
        }
    }
    __syncthreads();   // B1: X published

    // ---------- phase 1a: V GEMM (normal orientation, r5-proven) ----------
    uint32_t vd[4][2][2];   // vd[mt][ntl][p] = V[16mt+4g+2p+{0,1}][ntl*16+l15]
    {
        v4f vacc[4][2];
        #pragma unroll
        for (int mt = 0; mt < 4; ++mt)
            #pragma unroll
            for (int ntl = 0; ntl < 2; ++ntl)
                vacc[mt][ntl] = (v4f){0.f,0.f,0.f,0.f};
        #pragma unroll
        for (int kk = 0; kk < 6; ++kk) {
            v8s xfr[4];
            #pragma unroll
            for (int mt = 0; mt < 4; ++mt) {
                int tok = mt*16 + l15;
                xfr[mt] = *(const v8s*)&bufX[tok*DIM + ((kk*32 + g*8) ^ SWZ(tok))];
            }
            #pragma unroll
            for (int ntl = 0; ntl < 2; ++ntl) {
                int o = 2*DIM + wv*32 + ntl*16 + l15;
                v8s wvf = *(const v8s*)(qw + (size_t)o*DIM + kk*32 + g*8);
                #pragma unroll
                for (int mt = 0; mt < 4; ++mt)
                    vacc[mt][ntl] = __builtin_amdgcn_mfma_f32_16x16x32_bf16(xfr[mt], wvf, vacc[mt][ntl], 0, 0, 0);
            }
        }
        #pragma unroll
        for (int ntl = 0; ntl < 2; ++ntl) {
            const float bv = qb2[2*DIM + wv*32 + ntl*16 + l15];
            #pragma unroll
            for (int mt = 0; mt < 4; ++mt) {
                vd[mt][ntl][0] = pk2(vacc[mt][ntl][0]+bv, vacc[mt][ntl][1]+bv);
                vd[mt][ntl][1] = pk2(vacc[mt][ntl][2]+bv, vacc[mt][ntl][3]+bv);
            }
        }
    }

    // ---------- phase 1b: Q^T GEMM (transposed; 32-acc) ----------
    v8s qfr[4];
    {
        v4f qacc[2][4];
        #pragma unroll
        for (int ntl = 0; ntl < 2; ++ntl)
            #pragma unroll
            for (int qt = 0; qt < 4; ++qt)
                qacc[ntl][qt] = (v4f){0.f,0.f,0.f,0.f};
        #pragma unroll
        for (int kk = 0; kk < 6; ++kk) {
            v8s xfr[4];
            #pragma unroll
            for (int qt = 0; qt < 4; ++qt) {
                int tok = qt*16 + l15;
                xfr[qt] = *(const v8s*)&bufX[tok*DIM + ((kk*32 + g*8) ^ SWZ(tok))];
            }
            #pragma unroll
            for (int ntl = 0; ntl < 2; ++ntl) {
                v8s wq = *(const v8s*)(qw + (size_t)(wv*32 + ntl*16 + l15)*DIM + kk*32 + g*8);
                #pragma unroll
                for (int qt = 0; qt < 4; ++qt)
                    qacc[ntl][qt] = __builtin_amdgcn_mfma_f32_16x16x32_bf16(wq, xfr[qt], qacc[ntl][qt], 0, 0, 0);
            }
        }
        v4f bqv[2];
        #pragma unroll
        for (int ntl = 0; ntl < 2; ++ntl)
            bqv[ntl] = *(const v4f*)&qb2[wv*32 + ntl*16 + 4*g];
        #pragma unroll
        for (int qt = 0; qt < 4; ++qt) {
            union { v8s v; uint32_t d[4]; } uq;
            uq.d[0] = pk2(qacc[0][qt][0]+bqv[0][0], qacc[0][qt][1]+bqv[0][1]);
            uq.d[1] = pk2(qacc[0][qt][2]+bqv[0][2], qacc[0][qt][3]+bqv[0][3]);
            uq.d[2] = pk2(qacc[1][qt][0]+bqv[1][0], qacc[1][qt][1]+bqv[1][1]);
            uq.d[3] = pk2(qacc[1][qt][2]+bqv[1][2], qacc[1][qt][3]+bqv[1][3]);
            qfr[qt] = uq.v;
        }
    }

    // ---------- phase 1c: K^T GEMM (same structure) ----------
    v8s kfr[4];
    {
        v4f kacc[2][4];
        #pragma unroll
        for (int ntl = 0; ntl < 2; ++ntl)
            #pragma unroll
            for (int kt = 0; kt < 4; ++kt)
                kacc[ntl][kt] = (v4f){0.f,0.f,0.f,0.f};
        #pragma unroll
        for (int kk = 0; kk < 6; ++kk) {
            v8s xfr[4];
            #pragma unroll
            for (int kt = 0; kt < 4; ++kt) {
                int tok = kt*16 + l15;
                xfr[kt] = *(const v8s*)&bufX[tok*DIM + ((kk*32 + g*8) ^ SWZ(tok))];
            }
            #pragma unroll
            for (int ntl = 0; ntl < 2; ++ntl) {
                v8s wk = *(const v8s*)(qw + (size_t)(DIM + wv*32 + ntl*16 + l15)*DIM + kk*32 + g*8);
                #pragma unroll
                for (int kt = 0; kt < 4; ++kt)
                    kacc[ntl][kt] = __builtin_amdgcn_mfma_f32_16x16x32_bf16(wk, xfr[kt], kacc[ntl][kt], 0, 0, 0);
            }
        }
        v4f bkv[2];
        #pragma unroll
        for (int ntl = 0; ntl < 2; ++ntl)
            bkv[ntl] = *(const v4f*)&qb2[DIM + wv*32 + ntl*16 + 4*g];
        #pragma unroll
        for (int kt = 0; kt < 4; ++kt) {
            union { v8s v; uint32_t d[4]; } uk;
            uk.d[0] = pk2(kacc[0][kt][0]+bkv[0][0], kacc[0][kt][1]+bkv[0][1]);
            uk.d[1] = pk2(kacc[0][kt][2]+bkv[0][2], kacc[0][kt][3]+bkv[0][3]);
            uk.d[2] = pk2(kacc[1][kt][0]+bkv[1][0], kacc[1][kt][1]+bkv[1][1]);
            uk.d[3] = pk2(kacc[1][kt][2]+bkv[1][2], kacc[1][kt][3]+bkv[1][3]);
            kfr[kt] = uk.v;
        }
    }

    // ---------- phase 2: attention, per-qt interleave to cap live accumulators ----------
    // S^T column group qt: sq[kt][r] = S[key=16kt+4g+r][query=16qt+l15]; softmax; pack to pd.
    uint32_t pd[2][4][4];   // pd[kk][qt][*] — identical layout to r9's p.d
    const float* bt = biasT + wv*4096;
    #pragma unroll
    for (int qt = 0; qt < 4; ++qt) {
        v4f sq[4];
        #pragma unroll
        for (int kt = 0; kt < 4; ++kt)
            sq[kt] = __builtin_amdgcn_mfma_f32_16x16x32_bf16(kfr[kt], qfr[qt],
                         (v4f){0.f,0.f,0.f,0.f}, 0, 0, 0);
        #pragma unroll
        for (int kt = 0; kt < 4; ++kt) {
            v4f bb = *(const v4f*)&bt[(qt*16 + l15)*64 + kt*16 + 4*g];
            sq[kt] += bb;
        }
        float mx = sq[0][0];
        #pragma unroll
        for (int kt = 0; kt < 4; ++kt)
            #pragma unroll
            for (int r = 0; r < 4; ++r) mx = fmaxf(mx, sq[kt][r]);
        mx = fmaxf(mx, __shfl_xor(mx, 16));
        mx = fmaxf(mx, __shfl_xor(mx, 32));
        float sum = 0.f;
        #pragma unroll
        for (int kt = 0; kt < 4; ++kt)
            #pragma unroll
            for (int r = 0; r < 4; ++r) {
                float e = __expf(sq[kt][r] - mx);
                sq[kt][r] = e; sum += e;
            }
        sum += __shfl_xor(sum, 16);
        sum += __shfl_xor(sum, 32);
        float inv = 1.f / sum;
        #pragma unroll
        for (int kt = 0; kt < 4; ++kt)
            #pragma unroll
            for (int r = 0; r < 4; ++r) sq[kt][r] *= inv;

        pd[0][qt][0] = pk2(sq[0][0], sq[0][1]);
        pd[0][qt][1] = pk2(sq[0][2], sq[0][3]);
        pd[0][qt][2] = pk2(sq[1][0], sq[1][1]);
        pd[0][qt][3] = pk2(sq[1][2], sq[1][3]);
        pd[1][qt][0] = pk2(sq[2][0], sq[2][1]);
        pd[1][qt][1] = pk2(sq[2][2], sq[2][3]);
        pd[1][qt][2] = pk2(sq[3][0], sq[3][1]);
        pd[1][qt][3] = pk2(sq[3][2], sq[3][3]);
    }

    // O^T = V^T P^T via register repacks; slot (g,j) <-> key 16*(2kk+(j>>2))+4g+(j&3)
    v4f oT[2][4];   // [ntl][qt]: O[query=16qt+l15][d=16ntl+4g+r]
    #pragma unroll
    for (int ntl = 0; ntl < 2; ++ntl)
        #pragma unroll
        for (int qt = 0; qt < 4; ++qt)
            oT[ntl][qt] = (v4f){0.f,0.f,0.f,0.f};
    #pragma unroll
    for (int kk = 0; kk < 2; ++kk) {
        v8s vfr[2];
        #pragma unroll
        for (int ntl = 0; ntl < 2; ++ntl) {
            union { v8s v; uint32_t d[4]; } uu;
            uu.d[0] = vd[2*kk  ][ntl][0]; uu.d[1] = vd[2*kk  ][ntl][1];
            uu.d[2] = vd[2*kk+1][ntl][0]; uu.d[3] = vd[2*kk+1][ntl][1];
            vfr[ntl] = uu.v;
        }
        #pragma unroll
        for (int qt = 0; qt < 4; ++qt) {
            union { v8s v; uint32_t d[4]; } p;
            p.d[0] = pd[kk][qt][0]; p.d[1] = pd[kk][qt][1];
            p.d[2] = pd[kk][qt][2]; p.d[3] = pd[kk][qt][3];
            #pragma unroll
            for (int ntl = 0; ntl < 2; ++ntl)
                oT[ntl][qt] = __builtin_amdgcn_mfma_f32_16x16x32_bf16(vfr[ntl], p.v, oT[ntl][qt], 0, 0, 0);
        }
    }

    // attn_out -> bufO [64][AO_STR], b64 stores
    #pragma unroll
    for (int qt = 0; qt < 4; ++qt)
        #pragma unroll
        for (int ntl = 0; ntl < 2; ++ntl) {
            v2u o;
            o.x = pk2(oT[ntl][qt][0], oT[ntl][qt][1]);
            o.y = pk2(oT[ntl][qt][2], oT[ntl][qt][3]);
            *(v2u*)&bufO[(qt*16 + l15)*AO_STR + wv*32 + ntl*16 + 4*g] = o;
        }
    __syncthreads();   // B2: AO complete

    // ---------- phase 3: transposed proj GEMM + direct register scatter (r5-proven) ----------
    v4f pacc[2][4];    // [ntl][qt]: P[out=wv*32+16ntl+4g+r][tok=16qt+l15]
    #pragma unroll
    for (int ntl = 0; ntl < 2; ++ntl)
        #pragma unroll
        for (int qt = 0; qt < 4; ++qt)
            pacc[ntl][qt] = (v4f){0.f,0.f,0.f,0.f};
    #pragma unroll
    for (int kk = 0; kk < 6; ++kk) {
        v8s aofr[4];
        #pragma unroll
        for (int qt = 0; qt < 4; ++qt)
            aofr[qt] = *(const v8s*)&bufO[(qt*16 + l15)*AO_STR + kk*32 + g*8];
        #pragma unroll
        for (int ntl = 0; ntl < 2; ++ntl) {
            v8s pwfr = *(const v8s*)(pw + (size_t)(wv*32 + ntl*16 + l15)*DIM + kk*32 + g*8);
            #pragma unroll
            for (int qt = 0; qt < 4; ++qt)
                pacc[ntl][qt] = __builtin_amdgcn_mfma_f32_16x16x32_bf16(pwfr, aofr[qt], pacc[ntl][qt], 0, 0, 0);
        }
    }
    float pb[2][4];
    #pragma unroll
    for (int ntl = 0; ntl < 2; ++ntl) {
        v4f pbv = *(const v4f*)&proj_b[wv*32 + ntl*16 + 4*g];
        #pragma unroll
        for (int r = 0; r < 4; ++r) pb[ntl][r] = pbv[r];
    }

    float* ob = out + (size_t)b * DIM*IMG*IMG;
    #pragma unroll
    for (int qt = 0; qt < 4; ++qt) {
        const int strow = 2*qt + (l15 >> 3);
        const int stcol = l15 & 7;
        int hh = wi*8 + strow + 4; if (hh >= IMG) hh -= IMG;
        int ww = wj*8 + stcol + 4; if (ww >= IMG) ww -= IMG;
        const size_t pix = (size_t)hh*IMG + ww;
        #pragma unroll
        for (int ntl = 0; ntl < 2; ++ntl)
            #pragma unroll
            for (int r = 0; r < 4; ++r) {
                const int c = wv*32 + ntl*16 + 4*g + r;
                ob[(size_t)c*(IMG*IMG) + pix] = pacc[ntl][qt][r] + pb[ntl][r];
            }
    }
}

extern "C" void kernel_launch(void* const* d_in, const int* in_sizes, int n_in,
                              void* d_out, int out_size, void* d_ws, size_t ws_size,
                              hipStream_t stream) {
    const float* x        = (const float*)d_in[0];
    const float* qkv_w    = (const float*)d_in[1];
    const float* qkv_b    = (const float*)d_in[2];
    const float* proj_w   = (const float*)d_in[3];
    const float* proj_b   = (const float*)d_in[4];
    const float* rel_bias = (const float*)d_in[5];
    const int*   rel_idx  = (const int*)d_in[6];

    u16*   qw_bf  = (u16*)d_ws;                         // 221184 B
    u16*   pw_bf  = (u16*)((char*)d_ws + 221184);       //  73728 B
    float* qb2    = (float*)((char*)d_ws + 294912);     //   2304 B
    float* biasT  = (float*)((char*)d_ws + 297216);     //  98304 B
    float* out    = (float*)d_out;

    hipLaunchKernelGGL(prep_kernel, dim3(432), dim3(256), 0, stream,
                       qkv_w, qkv_b, proj_w, rel_bias, rel_idx, qw_bf, pw_bf, qb2, biasT);
    hipLaunchKernelGGL(winattn_kernel, dim3(NWINDOWS), dim3(384), 0, stream,
                       x, proj_b, qw_bf, pw_bf, qb2, biasT, out);
}

// Round 12
// 515.960 us; speedup vs baseline: 2.1648x; 1.2403x over previous
//
#include <hip/hip_runtime.h>
#include <hip/hip_bf16.h>
#include <stdint.h>

typedef unsigned short u16;
typedef short v8s __attribute__((ext_vector_type(8)));
typedef float v4f __attribute__((ext_vector_type(4)));
typedef uint32_t v2u __attribute__((ext_vector_type(2)));

#define DIM 192
#define NH 6
#define IMG 224
#define NWIN 28
#define NB 8
#define SCALE 0.17677669529663687f
#define AO_STR 200   // bf16 stride for attn_out tile

// X-tile swizzle (r9-proven): bijective per token, halves gather-store conflicts
#define SWZ(tok) ((((tok) & 7) ^ ((tok) >> 3)) << 3)

__device__ __forceinline__ u16 f2bf(float f) {
    union { __hip_bfloat16 b; u16 u; } c; c.b = __float2bfloat16(f); return c.u;
}
__device__ __forceinline__ uint32_t pk2(float lo, float hi) {
    union { __hip_bfloat162 b; uint32_t u; } c;
    c.b = __float22bfloat162_rn(make_float2(lo, hi));
    return c.u;
}

// ---- prep: bf16 weights (SCALE folded into q rows), scaled bias, expanded bias table ----
__global__ void prep_kernel(const float* __restrict__ qkv_w,
                            const float* __restrict__ qkv_b,
                            const float* __restrict__ proj_w,
                            const float* __restrict__ rel_bias,
                            const int* __restrict__ rel_idx,
                            u16* __restrict__ qw, u16* __restrict__ pw,
                            float* __restrict__ qb2, float* __restrict__ biasT) {
    int i = blockIdx.x * 256 + threadIdx.x;
    if (i < 3*DIM*DIM) {
        float s = (i < DIM*DIM) ? SCALE : 1.f;
        qw[i] = f2bf(qkv_w[i] * s);
    }
    if (i < DIM*DIM) pw[i] = f2bf(proj_w[i]);
    if (i < 3*DIM)   qb2[i] = qkv_b[i] * (i < DIM ? SCALE : 1.f);
    if (i < NH*64*64) {
        int h   = i >> 12;          // biasT[h][query][key], key minor
        int qk2 = i & 4095;
        biasT[i] = rel_bias[rel_idx[qk2]*NH + h];
    }
}

// ---- fused window attention: one block = 2 adjacent windows x 6 heads = 12 waves ----
__global__ __launch_bounds__(768, 3) void winattn_kernel(
    const float* __restrict__ x,
    const float* __restrict__ proj_b,
    const u16* __restrict__ qw,
    const u16* __restrict__ pw,
    const float* __restrict__ qb2,
    const float* __restrict__ biasT,
    float* __restrict__ out)
{
    __shared__ __align__(16) u16 bufX[2][64 * DIM];     // 2 x 24576 B
    __shared__ __align__(16) u16 bufO[2][64 * AO_STR];  // 2 x 25600 B  (total 100352 B)

    const int tid  = threadIdx.x;
    const int wv   = tid >> 6;          // 0..11
    const int h    = wv >> 1;           // head 0..5
    const int win  = wv & 1;            // window parity 0..1
    const int lane = tid & 63;
    const int l15  = lane & 15;
    const int g    = lane >> 4;

    // XCD swizzle: dispatch i -> XCD i%8; each XCD gets one full image (392 pairs)
    const int b  = blockIdx.x & 7;
    const int rm = blockIdx.x >> 3;     // 0..391 -> windows {2rm, 2rm+1} (wj-adjacent)

    const float* xb = x   + (size_t)b * DIM*IMG*IMG;
    float*       ob = out + (size_t)b * DIM*IMG*IMG;

    // ---------- phase 0: gather (float4); 384-thread half per window ----------
    {
        const int gwin = (tid >= 384) ? 1 : 0;
        const int tl   = tid - gwin*384;
        const int widx = rm*2 + gwin;
        const int gwi  = widx / NWIN, gwj = widx - gwi*NWIN;
        const int qq   = tl & 15;
        const int trow = qq >> 1;
        const int tcol = (qq & 1) * 4;
        const int t0   = trow*8 + tcol;
        const int c0   = tl >> 4;           // 0..23
        int ghh = gwi*8 + trow + 4; if (ghh >= IMG) ghh -= IMG;   // roll(-4) folded in
        int gww = gwj*8 + tcol + 4; if (gww >= IMG) gww -= IMG;   // 16B vec never straddles wrap
        const size_t pixoff = (size_t)ghh*IMG + gww;

        v4f buf[8];
        #pragma unroll
        for (int it = 0; it < 8; ++it)
            buf[it] = *(const v4f*)(xb + (size_t)(c0 + it*24)*(IMG*IMG) + pixoff);
        u16* bX = bufX[gwin];
        #pragma unroll
        for (int it = 0; it < 8; ++it) {
            int c = c0 + it*24;
            #pragma unroll
            for (int i = 0; i < 4; ++i) {
                int tok = t0 + i;
                bX[tok*DIM + (c ^ SWZ(tok))] = f2bf(buf[it][i]);
            }
        }
    }
    __syncthreads();   // B1: both X tiles published

    // compute-side window coords
    const int widx = rm*2 + win;
    const int wi = widx / NWIN, wj = widx - wi*NWIN;
    u16* bX = bufX[win];
    u16* bO = bufO[win];

    // ---------- phase 1a: V GEMM (normal orientation, r5-proven) ----------
    uint32_t vd[4][2][2];   // vd[mt][ntl][p] = V[16mt+4g+2p+{0,1}][ntl*16+l15]
    {
        v4f vacc[4][2];
        #pragma unroll
        for (int mt = 0; mt < 4; ++mt)
            #pragma unroll
            for (int ntl = 0; ntl < 2; ++ntl)
                vacc[mt][ntl] = (v4f){0.f,0.f,0.f,0.f};
        #pragma unroll
        for (int kk = 0; kk < 6; ++kk) {
            v8s xfr[4];
            #pragma unroll
            for (int mt = 0; mt < 4; ++mt) {
                int tok = mt*16 + l15;
                xfr[mt] = *(const v8s*)&bX[tok*DIM + ((kk*32 + g*8) ^ SWZ(tok))];
            }
            #pragma unroll
            for (int ntl = 0; ntl < 2; ++ntl) {
                int o = 2*DIM + h*32 + ntl*16 + l15;
                v8s wvf = *(const v8s*)(qw + (size_t)o*DIM + kk*32 + g*8);
                #pragma unroll
                for (int mt = 0; mt < 4; ++mt)
                    vacc[mt][ntl] = __builtin_amdgcn_mfma_f32_16x16x32_bf16(xfr[mt], wvf, vacc[mt][ntl], 0, 0, 0);
            }
        }
        #pragma unroll
        for (int ntl = 0; ntl < 2; ++ntl) {
            const float bv = qb2[2*DIM + h*32 + ntl*16 + l15];
            #pragma unroll
            for (int mt = 0; mt < 4; ++mt) {
                vd[mt][ntl][0] = pk2(vacc[mt][ntl][0]+bv, vacc[mt][ntl][1]+bv);
                vd[mt][ntl][1] = pk2(vacc[mt][ntl][2]+bv, vacc[mt][ntl][3]+bv);
            }
        }
    }

    // ---------- phase 1b: Q^T GEMM (transposed; 32-acc) ----------
    v8s qfr[4];
    {
        v4f qacc[2][4];
        #pragma unroll
        for (int ntl = 0; ntl < 2; ++ntl)
            #pragma unroll
            for (int qt = 0; qt < 4; ++qt)
                qacc[ntl][qt] = (v4f){0.f,0.f,0.f,0.f};
        #pragma unroll
        for (int kk = 0; kk < 6; ++kk) {
            v8s xfr[4];
            #pragma unroll
            for (int qt = 0; qt < 4; ++qt) {
                int tok = qt*16 + l15;
                xfr[qt] = *(const v8s*)&bX[tok*DIM + ((kk*32 + g*8) ^ SWZ(tok))];
            }
            #pragma unroll
            for (int ntl = 0; ntl < 2; ++ntl) {
                v8s wq = *(const v8s*)(qw + (size_t)(h*32 + ntl*16 + l15)*DIM + kk*32 + g*8);
                #pragma unroll
                for (int qt = 0; qt < 4; ++qt)
                    qacc[ntl][qt] = __builtin_amdgcn_mfma_f32_16x16x32_bf16(wq, xfr[qt], qacc[ntl][qt], 0, 0, 0);
            }
        }
        v4f bqv[2];
        #pragma unroll
        for (int ntl = 0; ntl < 2; ++ntl)
            bqv[ntl] = *(const v4f*)&qb2[h*32 + ntl*16 + 4*g];
        #pragma unroll
        for (int qt = 0; qt < 4; ++qt) {
            union { v8s v; uint32_t d[4]; } uq;
            uq.d[0] = pk2(qacc[0][qt][0]+bqv[0][0], qacc[0][qt][1]+bqv[0][1]);
            uq.d[1] = pk2(qacc[0][qt][2]+bqv[0][2], qacc[0][qt][3]+bqv[0][3]);
            uq.d[2] = pk2(qacc[1][qt][0]+bqv[1][0], qacc[1][qt][1]+bqv[1][1]);
            uq.d[3] = pk2(qacc[1][qt][2]+bqv[1][2], qacc[1][qt][3]+bqv[1][3]);
            qfr[qt] = uq.v;
        }
    }

    // ---------- phase 1c: K^T GEMM (same structure) ----------
    v8s kfr[4];
    {
        v4f kacc[2][4];
        #pragma unroll
        for (int ntl = 0; ntl < 2; ++ntl)
            #pragma unroll
            for (int kt = 0; kt < 4; ++kt)
                kacc[ntl][kt] = (v4f){0.f,0.f,0.f,0.f};
        #pragma unroll
        for (int kk = 0; kk < 6; ++kk) {
            v8s xfr[4];
            #pragma unroll
            for (int kt = 0; kt < 4; ++kt) {
                int tok = kt*16 + l15;
                xfr[kt] = *(const v8s*)&bX[tok*DIM + ((kk*32 + g*8) ^ SWZ(tok))];
            }
            #pragma unroll
            for (int ntl = 0; ntl < 2; ++ntl) {
                v8s wk = *(const v8s*)(qw + (size_t)(DIM + h*32 + ntl*16 + l15)*DIM + kk*32 + g*8);
                #pragma unroll
                for (int kt = 0; kt < 4; ++kt)
                    kacc[ntl][kt] = __builtin_amdgcn_mfma_f32_16x16x32_bf16(wk, xfr[kt], kacc[ntl][kt], 0, 0, 0);
            }
        }
        v4f bkv[2];
        #pragma unroll
        for (int ntl = 0; ntl < 2; ++ntl)
            bkv[ntl] = *(const v4f*)&qb2[DIM + h*32 + ntl*16 + 4*g];
        #pragma unroll
        for (int kt = 0; kt < 4; ++kt) {
            union { v8s v; uint32_t d[4]; } uk;
            uk.d[0] = pk2(kacc[0][kt][0]+bkv[0][0], kacc[0][kt][1]+bkv[0][1]);
            uk.d[1] = pk2(kacc[0][kt][2]+bkv[0][2], kacc[0][kt][3]+bkv[0][3]);
            uk.d[2] = pk2(kacc[1][kt][0]+bkv[1][0], kacc[1][kt][1]+bkv[1][1]);
            uk.d[3] = pk2(kacc[1][kt][2]+bkv[1][2], kacc[1][kt][3]+bkv[1][3]);
            kfr[kt] = uk.v;
        }
    }

    // ---------- phase 2: attention, per-qt interleave (r11-proven) ----------
    uint32_t pd[2][4][4];
    const float* bt = biasT + h*4096;
    #pragma unroll
    for (int qt = 0; qt < 4; ++qt) {
        v4f sq[4];
        #pragma unroll
        for (int kt = 0; kt < 4; ++kt)
            sq[kt] = __builtin_amdgcn_mfma_f32_16x16x32_bf16(kfr[kt], qfr[qt],
                         (v4f){0.f,0.f,0.f,0.f}, 0, 0, 0);
        #pragma unroll
        for (int kt = 0; kt < 4; ++kt) {
            v4f bb = *(const v4f*)&bt[(qt*16 + l15)*64 + kt*16 + 4*g];
            sq[kt] += bb;
        }
        float mx = sq[0][0];
        #pragma unroll
        for (int kt = 0; kt < 4; ++kt)
            #pragma unroll
            for (int r = 0; r < 4; ++r) mx = fmaxf(mx, sq[kt][r]);
        mx = fmaxf(mx, __shfl_xor(mx, 16));
        mx = fmaxf(mx, __shfl_xor(mx, 32));
        float sum = 0.f;
        #pragma unroll
        for (int kt = 0; kt < 4; ++kt)
            #pragma unroll
            for (int r = 0; r < 4; ++r) {
                float e = __expf(sq[kt][r] - mx);
                sq[kt][r] = e; sum += e;
            }
        sum += __shfl_xor(sum, 16);
        sum += __shfl_xor(sum, 32);
        float inv = 1.f / sum;
        #pragma unroll
        for (int kt = 0; kt < 4; ++kt)
            #pragma unroll
            for (int r = 0; r < 4; ++r) sq[kt][r] *= inv;

        pd[0][qt][0] = pk2(sq[0][0], sq[0][1]);
        pd[0][qt][1] = pk2(sq[0][2], sq[0][3]);
        pd[0][qt][2] = pk2(sq[1][0], sq[1][1]);
        pd[0][qt][3] = pk2(sq[1][2], sq[1][3]);
        pd[1][qt][0] = pk2(sq[2][0], sq[2][1]);
        pd[1][qt][1] = pk2(sq[2][2], sq[2][3]);
        pd[1][qt][2] = pk2(sq[3][0], sq[3][1]);
        pd[1][qt][3] = pk2(sq[3][2], sq[3][3]);
    }

    // O^T = V^T P^T via register repacks; slot (g,j) <-> key 16*(2kk+(j>>2))+4g+(j&3)
    v4f oT[2][4];
    #pragma unroll
    for (int ntl = 0; ntl < 2; ++ntl)
        #pragma unroll
        for (int qt = 0; qt < 4; ++qt)
            oT[ntl][qt] = (v4f){0.f,0.f,0.f,0.f};
    #pragma unroll
    for (int kk = 0; kk < 2; ++kk) {
        v8s vfr[2];
        #pragma unroll
        for (int ntl = 0; ntl < 2; ++ntl) {
            union { v8s v; uint32_t d[4]; } uu;
            uu.d[0] = vd[2*kk  ][ntl][0]; uu.d[1] = vd[2*kk  ][ntl][1];
            uu.d[2] = vd[2*kk+1][ntl][0]; uu.d[3] = vd[2*kk+1][ntl][1];
            vfr[ntl] = uu.v;
        }
        #pragma unroll
        for (int qt = 0; qt < 4; ++qt) {
            union { v8s v; uint32_t d[4]; } p;
            p.d[0] = pd[kk][qt][0]; p.d[1] = pd[kk][qt][1];
            p.d[2] = pd[kk][qt][2]; p.d[3] = pd[kk][qt][3];
            #pragma unroll
            for (int ntl = 0; ntl < 2; ++ntl)
                oT[ntl][qt] = __builtin_amdgcn_mfma_f32_16x16x32_bf16(vfr[ntl], p.v, oT[ntl][qt], 0, 0, 0);
        }
    }

    // attn_out -> bO [64][AO_STR], b64 stores
    #pragma unroll
    for (int qt = 0; qt < 4; ++qt)
        #pragma unroll
        for (int ntl = 0; ntl < 2; ++ntl) {
            v2u o;
            o.x = pk2(oT[ntl][qt][0], oT[ntl][qt][1]);
            o.y = pk2(oT[ntl][qt][2], oT[ntl][qt][3]);
            *(v2u*)&bO[(qt*16 + l15)*AO_STR + h*32 + ntl*16 + 4*g] = o;
        }
    __syncthreads();   // B2: both AO tiles complete

    // ---------- phase 3: transposed proj GEMM + direct register scatter (r5-proven) ----------
    v4f pacc[2][4];
    #pragma unroll
    for (int ntl = 0; ntl < 2; ++ntl)
        #pragma unroll
        for (int qt = 0; qt < 4; ++qt)
            pacc[ntl][qt] = (v4f){0.f,0.f,0.f,0.f};
    #pragma unroll
    for (int kk = 0; kk < 6; ++kk) {
        v8s aofr[4];
        #pragma unroll
        for (int qt = 0; qt < 4; ++qt)
            aofr[qt] = *(const v8s*)&bO[(qt*16 + l15)*AO_STR + kk*32 + g*8];
        #pragma unroll
        for (int ntl = 0; ntl < 2; ++ntl) {
            v8s pwfr = *(const v8s*)(pw + (size_t)(h*32 + ntl*16 + l15)*DIM + kk*32 + g*8);
            #pragma unroll
            for (int qt = 0; qt < 4; ++qt)
                pacc[ntl][qt] = __builtin_amdgcn_mfma_f32_16x16x32_bf16(pwfr, aofr[qt], pacc[ntl][qt], 0, 0, 0);
        }
    }
    float pb[2][4];
    #pragma unroll
    for (int ntl = 0; ntl < 2; ++ntl) {
        v4f pbv = *(const v4f*)&proj_b[h*32 + ntl*16 + 4*g];
        #pragma unroll
        for (int r = 0; r < 4; ++r) pb[ntl][r] = pbv[r];
    }

    #pragma unroll
    for (int qt = 0; qt < 4; ++qt) {
        const int strow = 2*qt + (l15 >> 3);
        const int stcol = l15 & 7;
        int hh = wi*8 + strow + 4; if (hh >= IMG) hh -= IMG;
        int ww = wj*8 + stcol + 4; if (ww >= IMG) ww -= IMG;
        const size_t pix = (size_t)hh*IMG + ww;
        #pragma unroll
        for (int ntl = 0; ntl < 2; ++ntl)
            #pragma unroll
            for (int r = 0; r < 4; ++r) {
                const int c = h*32 + ntl*16 + 4*g + r;
                ob[(size_t)c*(IMG*IMG) + pix] = pacc[ntl][qt][r] + pb[ntl][r];
            }
    }
}

extern "C" void kernel_launch(void* const* d_in, const int* in_sizes, int n_in,
                              void* d_out, int out_size, void* d_ws, size_t ws_size,
                              hipStream_t stream) {
    const float* x        = (const float*)d_in[0];
    const float* qkv_w    = (const float*)d_in[1];
    const float* qkv_b    = (const float*)d_in[2];
    const float* proj_w   = (const float*)d_in[3];
    const float* proj_b   = (const float*)d_in[4];
    const float* rel_bias = (const float*)d_in[5];
    const int*   rel_idx  = (const int*)d_in[6];

    u16*   qw_bf  = (u16*)d_ws;                         // 221184 B
    u16*   pw_bf  = (u16*)((char*)d_ws + 221184);       //  73728 B
    float* qb2    = (float*)((char*)d_ws + 294912);     //   2304 B
    float* biasT  = (float*)((char*)d_ws + 297216);     //  98304 B
    float* out    = (float*)d_out;

    hipLaunchKernelGGL(prep_kernel, dim3(432), dim3(256), 0, stream,
                       qkv_w, qkv_b, proj_w, rel_bias, rel_idx, qw_bf, pw_bf, qb2, biasT);
    hipLaunchKernelGGL(winattn_kernel, dim3(NB * (NWIN*NWIN/2)), dim3(768), 0, stream,
                       x, proj_b, qw_bf, pw_bf, qb2, biasT, out);
}

// Round 13
// 499.938 us; speedup vs baseline: 2.2341x; 1.0320x over previous
//
#include <hip/hip_runtime.h>
#include <hip/hip_bf16.h>
#include <stdint.h>

typedef unsigned short u16;
typedef short v8s __attribute__((ext_vector_type(8)));
typedef float v4f __attribute__((ext_vector_type(4)));
typedef uint32_t v2u __attribute__((ext_vector_type(2)));

#define DIM 192
#define NH 6
#define IMG 224
#define NWIN 28
#define NB 8
#define SCALE 0.17677669529663687f
#define AO_STR 200   // bf16 stride for attn_out tile

// X-tile swizzle (r9-proven): bijective per token, halves gather-store conflicts
#define SWZ(tok) ((((tok) & 7) ^ ((tok) >> 3)) << 3)

__device__ __forceinline__ u16 f2bf(float f) {
    union { __hip_bfloat16 b; u16 u; } c; c.b = __float2bfloat16(f); return c.u;
}
__device__ __forceinline__ uint32_t pk2(float lo, float hi) {
    union { __hip_bfloat162 b; uint32_t u; } c;
    c.b = __float22bfloat162_rn(make_float2(lo, hi));
    return c.u;
}

// ---- prep: bf16 weights (SCALE folded into q rows), scaled bias, expanded bias table ----
__global__ void prep_kernel(const float* __restrict__ qkv_w,
                            const float* __restrict__ qkv_b,
                            const float* __restrict__ proj_w,
                            const float* __restrict__ rel_bias,
                            const int* __restrict__ rel_idx,
                            u16* __restrict__ qw, u16* __restrict__ pw,
                            float* __restrict__ qb2, float* __restrict__ biasT) {
    int i = blockIdx.x * 256 + threadIdx.x;
    if (i < 3*DIM*DIM) {
        float s = (i < DIM*DIM) ? SCALE : 1.f;
        qw[i] = f2bf(qkv_w[i] * s);
    }
    if (i < DIM*DIM) pw[i] = f2bf(proj_w[i]);
    if (i < 3*DIM)   qb2[i] = qkv_b[i] * (i < DIM ? SCALE : 1.f);
    if (i < NH*64*64) {
        int h   = i >> 12;          // biasT[h][query][key], key minor
        int qk2 = i & 4095;
        biasT[i] = rel_bias[rel_idx[qk2]*NH + h];
    }
}

// ---- fused window attention: one block = 2 adjacent windows x 6 heads = 12 waves ----
__global__ __launch_bounds__(768, 3) void winattn_kernel(
    const float* __restrict__ x,
    const float* __restrict__ proj_b,
    const u16* __restrict__ qw,
    const u16* __restrict__ pw,
    const float* __restrict__ qb2,
    const float* __restrict__ biasT,
    float* __restrict__ out)
{
    __shared__ __align__(16) u16 bufX[2][64 * DIM];     // 2 x 24576 B
    __shared__ __align__(16) u16 bufO[2][64 * AO_STR];  // 2 x 25600 B  (total 100352 B)

    const int tid  = threadIdx.x;
    const int wv   = tid >> 6;          // 0..11
    const int h    = wv >> 1;           // head 0..5
    const int win  = wv & 1;            // window parity 0..1
    const int lane = tid & 63;
    const int l15  = lane & 15;
    const int g    = lane >> 4;

    // XCD swizzle: dispatch i -> XCD i%8; each XCD gets one full image (392 pairs)
    const int b  = blockIdx.x & 7;
    const int rm = blockIdx.x >> 3;     // 0..391 -> windows {2rm, 2rm+1} (wj-adjacent)

    const float* xb = x   + (size_t)b * DIM*IMG*IMG;
    float*       ob = out + (size_t)b * DIM*IMG*IMG;

    // ---------- phase 0: gather (float4); 384-thread half per window ----------
    {
        const int gwin = (tid >= 384) ? 1 : 0;
        const int tl   = tid - gwin*384;
        const int widx = rm*2 + gwin;
        const int gwi  = widx / NWIN, gwj = widx - gwi*NWIN;
        const int qq   = tl & 15;
        const int trow = qq >> 1;
        const int tcol = (qq & 1) * 4;
        const int t0   = trow*8 + tcol;
        const int c0   = tl >> 4;           // 0..23
        int ghh = gwi*8 + trow + 4; if (ghh >= IMG) ghh -= IMG;   // roll(-4) folded in
        int gww = gwj*8 + tcol + 4; if (gww >= IMG) gww -= IMG;   // 16B vec never straddles wrap
        const size_t pixoff = (size_t)ghh*IMG + gww;

        v4f buf[8];
        #pragma unroll
        for (int it = 0; it < 8; ++it)
            buf[it] = *(const v4f*)(xb + (size_t)(c0 + it*24)*(IMG*IMG) + pixoff);
        u16* bX = bufX[gwin];
        #pragma unroll
        for (int it = 0; it < 8; ++it) {
            int c = c0 + it*24;
            #pragma unroll
            for (int i = 0; i < 4; ++i) {
                int tok = t0 + i;
                bX[tok*DIM + (c ^ SWZ(tok))] = f2bf(buf[it][i]);
            }
        }
    }
    __syncthreads();   // B1: both X tiles published

    // compute-side window coords
    const int widx = rm*2 + win;
    const int wi = widx / NWIN, wj = widx - wi*NWIN;
    u16* bX = bufX[win];
    u16* bO = bufO[win];

    // ---------- phase 1a: V GEMM (normal orientation, r5-proven) ----------
    uint32_t vd[4][2][2];   // vd[mt][ntl][p] = V[16mt+4g+2p+{0,1}][ntl*16+l15]
    {
        v4f vacc[4][2];
        #pragma unroll
        for (int mt = 0; mt < 4; ++mt)
            #pragma unroll
            for (int ntl = 0; ntl < 2; ++ntl)
                vacc[mt][ntl] = (v4f){0.f,0.f,0.f,0.f};
        #pragma unroll 2
        for (int kk = 0; kk < 6; ++kk) {
            v8s xfr[4];
            #pragma unroll
            for (int mt = 0; mt < 4; ++mt) {
                int tok = mt*16 + l15;
                xfr[mt] = *(const v8s*)&bX[tok*DIM + ((kk*32 + g*8) ^ SWZ(tok))];
            }
            v8s wvf[2];
            #pragma unroll
            for (int ntl = 0; ntl < 2; ++ntl)
                wvf[ntl] = *(const v8s*)(qw + (size_t)(2*DIM + h*32 + ntl*16 + l15)*DIM + kk*32 + g*8);
            __builtin_amdgcn_s_setprio(1);
            #pragma unroll
            for (int ntl = 0; ntl < 2; ++ntl)
                #pragma unroll
                for (int mt = 0; mt < 4; ++mt)
                    vacc[mt][ntl] = __builtin_amdgcn_mfma_f32_16x16x32_bf16(xfr[mt], wvf[ntl], vacc[mt][ntl], 0, 0, 0);
            __builtin_amdgcn_s_setprio(0);
        }
        #pragma unroll
        for (int ntl = 0; ntl < 2; ++ntl) {
            const float bv = qb2[2*DIM + h*32 + ntl*16 + l15];
            #pragma unroll
            for (int mt = 0; mt < 4; ++mt) {
                vd[mt][ntl][0] = pk2(vacc[mt][ntl][0]+bv, vacc[mt][ntl][1]+bv);
                vd[mt][ntl][1] = pk2(vacc[mt][ntl][2]+bv, vacc[mt][ntl][3]+bv);
            }
        }
    }

    // ---------- phase 1b: Q^T GEMM (transposed; 32-acc) ----------
    v8s qfr[4];
    {
        v4f qacc[2][4];
        #pragma unroll
        for (int ntl = 0; ntl < 2; ++ntl)
            #pragma unroll
            for (int qt = 0; qt < 4; ++qt)
                qacc[ntl][qt] = (v4f){0.f,0.f,0.f,0.f};
        #pragma unroll 2
        for (int kk = 0; kk < 6; ++kk) {
            v8s xfr[4];
            #pragma unroll
            for (int qt = 0; qt < 4; ++qt) {
                int tok = qt*16 + l15;
                xfr[qt] = *(const v8s*)&bX[tok*DIM + ((kk*32 + g*8) ^ SWZ(tok))];
            }
            v8s wq[2];
            #pragma unroll
            for (int ntl = 0; ntl < 2; ++ntl)
                wq[ntl] = *(const v8s*)(qw + (size_t)(h*32 + ntl*16 + l15)*DIM + kk*32 + g*8);
            __builtin_amdgcn_s_setprio(1);
            #pragma unroll
            for (int ntl = 0; ntl < 2; ++ntl)
                #pragma unroll
                for (int qt = 0; qt < 4; ++qt)
                    qacc[ntl][qt] = __builtin_amdgcn_mfma_f32_16x16x32_bf16(wq[ntl], xfr[qt], qacc[ntl][qt], 0, 0, 0);
            __builtin_amdgcn_s_setprio(0);
        }
        v4f bqv[2];
        #pragma unroll
        for (int ntl = 0; ntl < 2; ++ntl)
            bqv[ntl] = *(const v4f*)&qb2[h*32 + ntl*16 + 4*g];
        #pragma unroll
        for (int qt = 0; qt < 4; ++qt) {
            union { v8s v; uint32_t d[4]; } uq;
            uq.d[0] = pk2(qacc[0][qt][0]+bqv[0][0], qacc[0][qt][1]+bqv[0][1]);
            uq.d[1] = pk2(qacc[0][qt][2]+bqv[0][2], qacc[0][qt][3]+bqv[0][3]);
            uq.d[2] = pk2(qacc[1][qt][0]+bqv[1][0], qacc[1][qt][1]+bqv[1][1]);
            uq.d[3] = pk2(qacc[1][qt][2]+bqv[1][2], qacc[1][qt][3]+bqv[1][3]);
            qfr[qt] = uq.v;
        }
    }

    // ---------- phase 1c: K^T GEMM (same structure) ----------
    v8s kfr[4];
    {
        v4f kacc[2][4];
        #pragma unroll
        for (int ntl = 0; ntl < 2; ++ntl)
            #pragma unroll
            for (int kt = 0; kt < 4; ++kt)
                kacc[ntl][kt] = (v4f){0.f,0.f,0.f,0.f};
        #pragma unroll 2
        for (int kk = 0; kk < 6; ++kk) {
            v8s xfr[4];
            #pragma unroll
            for (int kt = 0; kt < 4; ++kt) {
                int tok = kt*16 + l15;
                xfr[kt] = *(const v8s*)&bX[tok*DIM + ((kk*32 + g*8) ^ SWZ(tok))];
            }
            v8s wk[2];
            #pragma unroll
            for (int ntl = 0; ntl < 2; ++ntl)
                wk[ntl] = *(const v8s*)(qw + (size_t)(DIM + h*32 + ntl*16 + l15)*DIM + kk*32 + g*8);
            __builtin_amdgcn_s_setprio(1);
            #pragma unroll
            for (int ntl = 0; ntl < 2; ++ntl)
                #pragma unroll
                for (int kt = 0; kt < 4; ++kt)
                    kacc[ntl][kt] = __builtin_amdgcn_mfma_f32_16x16x32_bf16(wk[ntl], xfr[kt], kacc[ntl][kt], 0, 0, 0);
            __builtin_amdgcn_s_setprio(0);
        }
        v4f bkv[2];
        #pragma unroll
        for (int ntl = 0; ntl < 2; ++ntl)
            bkv[ntl] = *(const v4f*)&qb2[DIM + h*32 + ntl*16 + 4*g];
        #pragma unroll
        for (int kt = 0; kt < 4; ++kt) {
            union { v8s v; uint32_t d[4]; } uk;
            uk.d[0] = pk2(kacc[0][kt][0]+bkv[0][0], kacc[0][kt][1]+bkv[0][1]);
            uk.d[1] = pk2(kacc[0][kt][2]+bkv[0][2], kacc[0][kt][3]+bkv[0][3]);
            uk.d[2] = pk2(kacc[1][kt][0]+bkv[1][0], kacc[1][kt][1]+bkv[1][1]);
            uk.d[3] = pk2(kacc[1][kt][2]+bkv[1][2], kacc[1][kt][3]+bkv[1][3]);
            kfr[kt] = uk.v;
        }
    }

    // ---------- phase 2: attention, per-qt interleave (r11-proven) ----------
    uint32_t pd[2][4][4];
    const float* bt = biasT + h*4096;
    #pragma unroll
    for (int qt = 0; qt < 4; ++qt) {
        v4f sq[4];
        __builtin_amdgcn_s_setprio(1);
        #pragma unroll
        for (int kt = 0; kt < 4; ++kt)
            sq[kt] = __builtin_amdgcn_mfma_f32_16x16x32_bf16(kfr[kt], qfr[qt],
                         (v4f){0.f,0.f,0.f,0.f}, 0, 0, 0);
        __builtin_amdgcn_s_setprio(0);
        #pragma unroll
        for (int kt = 0; kt < 4; ++kt) {
            v4f bb = *(const v4f*)&bt[(qt*16 + l15)*64 + kt*16 + 4*g];
            sq[kt] += bb;
        }
        float mx = sq[0][0];
        #pragma unroll
        for (int kt = 0; kt < 4; ++kt)
            #pragma unroll
            for (int r = 0; r < 4; ++r) mx = fmaxf(mx, sq[kt][r]);
        mx = fmaxf(mx, __shfl_xor(mx, 16));
        mx = fmaxf(mx, __shfl_xor(mx, 32));
        float sum = 0.f;
        #pragma unroll
        for (int kt = 0; kt < 4; ++kt)
            #pragma unroll
            for (int r = 0; r < 4; ++r) {
                float e = __expf(sq[kt][r] - mx);
                sq[kt][r] = e; sum += e;
            }
        sum += __shfl_xor(sum, 16);
        sum += __shfl_xor(sum, 32);
        float inv = 1.f / sum;
        #pragma unroll
        for (int kt = 0; kt < 4; ++kt)
            #pragma unroll
            for (int r = 0; r < 4; ++r) sq[kt][r] *= inv;

        pd[0][qt][0] = pk2(sq[0][0], sq[0][1]);
        pd[0][qt][1] = pk2(sq[0][2], sq[0][3]);
        pd[0][qt][2] = pk2(sq[1][0], sq[1][1]);
        pd[0][qt][3] = pk2(sq[1][2], sq[1][3]);
        pd[1][qt][0] = pk2(sq[2][0], sq[2][1]);
        pd[1][qt][1] = pk2(sq[2][2], sq[2][3]);
        pd[1][qt][2] = pk2(sq[3][0], sq[3][1]);
        pd[1][qt][3] = pk2(sq[3][2], sq[3][3]);
    }

    // O^T = V^T P^T via register repacks; slot (g,j) <-> key 16*(2kk+(j>>2))+4g+(j&3)
    v4f oT[2][4];
    #pragma unroll
    for (int ntl = 0; ntl < 2; ++ntl)
        #pragma unroll
        for (int qt = 0; qt < 4; ++qt)
            oT[ntl][qt] = (v4f){0.f,0.f,0.f,0.f};
    #pragma unroll
    for (int kk = 0; kk < 2; ++kk) {
        v8s vfr[2];
        #pragma unroll
        for (int ntl = 0; ntl < 2; ++ntl) {
            union { v8s v; uint32_t d[4]; } uu;
            uu.d[0] = vd[2*kk  ][ntl][0]; uu.d[1] = vd[2*kk  ][ntl][1];
            uu.d[2] = vd[2*kk+1][ntl][0]; uu.d[3] = vd[2*kk+1][ntl][1];
            vfr[ntl] = uu.v;
        }
        __builtin_amdgcn_s_setprio(1);
        #pragma unroll
        for (int qt = 0; qt < 4; ++qt) {
            union { v8s v; uint32_t d[4]; } p;
            p.d[0] = pd[kk][qt][0]; p.d[1] = pd[kk][qt][1];
            p.d[2] = pd[kk][qt][2]; p.d[3] = pd[kk][qt][3];
            #pragma unroll
            for (int ntl = 0; ntl < 2; ++ntl)
                oT[ntl][qt] = __builtin_amdgcn_mfma_f32_16x16x32_bf16(vfr[ntl], p.v, oT[ntl][qt], 0, 0, 0);
        }
        __builtin_amdgcn_s_setprio(0);
    }

    // attn_out -> bO [64][AO_STR], b64 stores
    #pragma unroll
    for (int qt = 0; qt < 4; ++qt)
        #pragma unroll
        for (int ntl = 0; ntl < 2; ++ntl) {
            v2u o;
            o.x = pk2(oT[ntl][qt][0], oT[ntl][qt][1]);
            o.y = pk2(oT[ntl][qt][2], oT[ntl][qt][3]);
            *(v2u*)&bO[(qt*16 + l15)*AO_STR + h*32 + ntl*16 + 4*g] = o;
        }
    __syncthreads();   // B2: both AO tiles complete

    // ---------- phase 3: transposed proj GEMM + direct register scatter (r5-proven) ----------
    v4f pacc[2][4];
    #pragma unroll
    for (int ntl = 0; ntl < 2; ++ntl)
        #pragma unroll
        for (int qt = 0; qt < 4; ++qt)
            pacc[ntl][qt] = (v4f){0.f,0.f,0.f,0.f};
    #pragma unroll 2
    for (int kk = 0; kk < 6; ++kk) {
        v8s aofr[4];
        #pragma unroll
        for (int qt = 0; qt < 4; ++qt)
            aofr[qt] = *(const v8s*)&bO[(qt*16 + l15)*AO_STR + kk*32 + g*8];
        v8s pwfr[2];
        #pragma unroll
        for (int ntl = 0; ntl < 2; ++ntl)
            pwfr[ntl] = *(const v8s*)(pw + (size_t)(h*32 + ntl*16 + l15)*DIM + kk*32 + g*8);
        __builtin_amdgcn_s_setprio(1);
        #pragma unroll
        for (int ntl = 0; ntl < 2; ++ntl)
            #pragma unroll
            for (int qt = 0; qt < 4; ++qt)
                pacc[ntl][qt] = __builtin_amdgcn_mfma_f32_16x16x32_bf16(pwfr[ntl], aofr[qt], pacc[ntl][qt], 0, 0, 0);
        __builtin_amdgcn_s_setprio(0);
    }
    float pb[2][4];
    #pragma unroll
    for (int ntl = 0; ntl < 2; ++ntl) {
        v4f pbv = *(const v4f*)&proj_b[h*32 + ntl*16 + 4*g];
        #pragma unroll
        for (int r = 0; r < 4; ++r) pb[ntl][r] = pbv[r];
    }

    #pragma unroll
    for (int qt = 0; qt < 4; ++qt) {
        const int strow = 2*qt + (l15 >> 3);
        const int stcol = l15 & 7;
        int hh = wi*8 + strow + 4; if (hh >= IMG) hh -= IMG;
        int ww = wj*8 + stcol + 4; if (ww >= IMG) ww -= IMG;
        const size_t pix = (size_t)hh*IMG + ww;
        #pragma unroll
        for (int ntl = 0; ntl < 2; ++ntl)
            #pragma unroll
            for (int r = 0; r < 4; ++r) {
                const int c = h*32 + ntl*16 + 4*g + r;
                ob[(size_t)c*(IMG*IMG) + pix] = pacc[ntl][qt][r] + pb[ntl][r];
            }
    }
}

extern "C" void kernel_launch(void* const* d_in, const int* in_sizes, int n_in,
                              void* d_out, int out_size, void* d_ws, size_t ws_size,
                              hipStream_t stream) {
    const float* x        = (const float*)d_in[0];
    const float* qkv_w    = (const float*)d_in[1];
    const float* qkv_b    = (const float*)d_in[2];
    const float* proj_w   = (const float*)d_in[3];
    const float* proj_b   = (const float*)d_in[4];
    const float* rel_bias = (const float*)d_in[5];
    const int*   rel_idx  = (const int*)d_in[6];

    u16*   qw_bf  = (u16*)d_ws;                         // 221184 B
    u16*   pw_bf  = (u16*)((char*)d_ws + 221184);       //  73728 B
    float* qb2    = (float*)((char*)d_ws + 294912);     //   2304 B
    float* biasT  = (float*)((char*)d_ws + 297216);     //  98304 B
    float* out    = (float*)d_out;

    hipLaunchKernelGGL(prep_kernel, dim3(432), dim3(256), 0, stream,
                       qkv_w, qkv_b, proj_w, rel_bias, rel_idx, qw_bf, pw_bf, qb2, biasT);
    hipLaunchKernelGGL(winattn_kernel, dim3(NB * (NWIN*NWIN/2)), dim3(768), 0, stream,
                       x, proj_b, qw_bf, pw_bf, qb2, biasT, out);
}

// Round 14
// 495.041 us; speedup vs baseline: 2.2562x; 1.0099x over previous
//
#include <hip/hip_runtime.h>
#include <hip/hip_bf16.h>
#include <stdint.h>

typedef unsigned short u16;
typedef short v8s __attribute__((ext_vector_type(8)));
typedef float v4f __attribute__((ext_vector_type(4)));
typedef uint32_t v2u __attribute__((ext_vector_type(2)));

#define DIM 192
#define NH 6
#define IMG 224
#define NWIN 28
#define NB 8
#define SCALE 0.17677669529663687f
#define AO_STR 200   // bf16 stride for attn_out tile

// X-tile swizzle (r9-proven): bijective per token, halves gather-store conflicts
#define SWZ(tok) ((((tok) & 7) ^ ((tok) >> 3)) << 3)

__device__ __forceinline__ u16 f2bf(float f) {
    union { __hip_bfloat16 b; u16 u; } c; c.b = __float2bfloat16(f); return c.u;
}
__device__ __forceinline__ uint32_t pk2(float lo, float hi) {
    union { __hip_bfloat162 b; uint32_t u; } c;
    c.b = __float22bfloat162_rn(make_float2(lo, hi));
    return c.u;
}

// ---- prep: bf16 weights (SCALE folded into q rows), scaled bias, expanded bias table ----
__global__ void prep_kernel(const float* __restrict__ qkv_w,
                            const float* __restrict__ qkv_b,
                            const float* __restrict__ proj_w,
                            const float* __restrict__ rel_bias,
                            const int* __restrict__ rel_idx,
                            u16* __restrict__ qw, u16* __restrict__ pw,
                            float* __restrict__ qb2, float* __restrict__ biasT) {
    int i = blockIdx.x * 256 + threadIdx.x;
    if (i < 3*DIM*DIM) {
        float s = (i < DIM*DIM) ? SCALE : 1.f;
        qw[i] = f2bf(qkv_w[i] * s);
    }
    if (i < DIM*DIM) pw[i] = f2bf(proj_w[i]);
    if (i < 3*DIM)   qb2[i] = qkv_b[i] * (i < DIM ? SCALE : 1.f);
    if (i < NH*64*64) {
        int h   = i >> 12;          // biasT[h][query][key], key minor
        int qk2 = i & 4095;
        biasT[i] = rel_bias[rel_idx[qk2]*NH + h];
    }
}

// ---- fused window attention: one block = 2 adjacent windows x 6 heads = 12 waves ----
__global__ __launch_bounds__(768, 3) void winattn_kernel(
    const float* __restrict__ x,
    const float* __restrict__ proj_b,
    const u16* __restrict__ qw,
    const u16* __restrict__ pw,
    const float* __restrict__ qb2,
    const float* __restrict__ biasT,
    float* __restrict__ out)
{
    __shared__ __align__(16) u16 bufX[2][64 * DIM];     // 2 x 24576 B
    __shared__ __align__(16) u16 bufO[2][64 * AO_STR];  // 2 x 25600 B  (total 100352 B)

    const int tid  = threadIdx.x;
    const int wv   = tid >> 6;          // 0..11
    const int h    = wv >> 1;           // head 0..5
    const int win  = wv & 1;            // window parity 0..1
    const int lane = tid & 63;
    const int l15  = lane & 15;
    const int g    = lane >> 4;

    // XCD swizzle: dispatch i -> XCD i%8; each XCD gets one full image (392 pairs)
    const int b  = blockIdx.x & 7;
    const int rm = blockIdx.x >> 3;     // 0..391 -> windows {2rm, 2rm+1} (wj-adjacent)

    const float* xb = x   + (size_t)b * DIM*IMG*IMG;
    float*       ob = out + (size_t)b * DIM*IMG*IMG;

    // ---------- phase 0: gather (float4); 384-thread half per window ----------
    {
        const int gwin = (tid >= 384) ? 1 : 0;
        const int tl   = tid - gwin*384;
        const int widx = rm*2 + gwin;
        const int gwi  = widx / NWIN, gwj = widx - gwi*NWIN;
        const int qq   = tl & 15;
        const int trow = qq >> 1;
        const int tcol = (qq & 1) * 4;
        const int t0   = trow*8 + tcol;
        const int c0   = tl >> 4;           // 0..23
        int ghh = gwi*8 + trow + 4; if (ghh >= IMG) ghh -= IMG;   // roll(-4) folded in
        int gww = gwj*8 + tcol + 4; if (gww >= IMG) gww -= IMG;   // 16B vec never straddles wrap
        const size_t pixoff = (size_t)ghh*IMG + gww;

        v4f buf[8];
        #pragma unroll
        for (int it = 0; it < 8; ++it)
            buf[it] = *(const v4f*)(xb + (size_t)(c0 + it*24)*(IMG*IMG) + pixoff);
        u16* bX = bufX[gwin];
        #pragma unroll
        for (int it = 0; it < 8; ++it) {
            int c = c0 + it*24;
            #pragma unroll
            for (int i = 0; i < 4; ++i) {
                int tok = t0 + i;
                bX[tok*DIM + (c ^ SWZ(tok))] = f2bf(buf[it][i]);
            }
        }
    }
    __syncthreads();   // B1: both X tiles published

    // compute-side window coords
    const int widx = rm*2 + win;
    const int wi = widx / NWIN, wj = widx - wi*NWIN;
    u16* bX = bufX[win];
    u16* bO = bufO[win];

    // ---------- phase 1a: V GEMM (normal orientation, r5-proven) ----------
    uint32_t vd[4][2][2];   // vd[mt][ntl][p] = V[16mt+4g+2p+{0,1}][ntl*16+l15]
    {
        v4f vacc[4][2];
        #pragma unroll
        for (int mt = 0; mt < 4; ++mt)
            #pragma unroll
            for (int ntl = 0; ntl < 2; ++ntl)
                vacc[mt][ntl] = (v4f){0.f,0.f,0.f,0.f};
        #pragma unroll
        for (int kk = 0; kk < 6; ++kk) {
            v8s xfr[4];
            #pragma unroll
            for (int mt = 0; mt < 4; ++mt) {
                int tok = mt*16 + l15;
                xfr[mt] = *(const v8s*)&bX[tok*DIM + ((kk*32 + g*8) ^ SWZ(tok))];
            }
            v8s wvf[2];
            #pragma unroll
            for (int ntl = 0; ntl < 2; ++ntl)
                wvf[ntl] = *(const v8s*)(qw + (size_t)(2*DIM + h*32 + ntl*16 + l15)*DIM + kk*32 + g*8);
            __builtin_amdgcn_s_setprio(1);
            #pragma unroll
            for (int ntl = 0; ntl < 2; ++ntl)
                #pragma unroll
                for (int mt = 0; mt < 4; ++mt)
                    vacc[mt][ntl] = __builtin_amdgcn_mfma_f32_16x16x32_bf16(xfr[mt], wvf[ntl], vacc[mt][ntl], 0, 0, 0);
            __builtin_amdgcn_s_setprio(0);
        }
        #pragma unroll
        for (int ntl = 0; ntl < 2; ++ntl) {
            const float bv = qb2[2*DIM + h*32 + ntl*16 + l15];
            #pragma unroll
            for (int mt = 0; mt < 4; ++mt) {
                vd[mt][ntl][0] = pk2(vacc[mt][ntl][0]+bv, vacc[mt][ntl][1]+bv);
                vd[mt][ntl][1] = pk2(vacc[mt][ntl][2]+bv, vacc[mt][ntl][3]+bv);
            }
        }
    }

    // ---------- phase 1bc: fused Q^T + K^T GEMM (r8-proven; one xfr feeds both) ----------
    v8s qfr[4], kfr[4];
    {
        v4f qacc[2][4], kacc[2][4];
        #pragma unroll
        for (int ntl = 0; ntl < 2; ++ntl)
            #pragma unroll
            for (int qt = 0; qt < 4; ++qt) {
                qacc[ntl][qt] = (v4f){0.f,0.f,0.f,0.f};
                kacc[ntl][qt] = (v4f){0.f,0.f,0.f,0.f};
            }
        #pragma unroll
        for (int kk = 0; kk < 6; ++kk) {
            v8s xfr[4];
            #pragma unroll
            for (int qt = 0; qt < 4; ++qt) {
                int tok = qt*16 + l15;
                xfr[qt] = *(const v8s*)&bX[tok*DIM + ((kk*32 + g*8) ^ SWZ(tok))];
            }
            v8s wq[2], wk[2];
            #pragma unroll
            for (int ntl = 0; ntl < 2; ++ntl) {
                wq[ntl] = *(const v8s*)(qw + (size_t)(h*32 + ntl*16 + l15)*DIM + kk*32 + g*8);
                wk[ntl] = *(const v8s*)(qw + (size_t)(DIM + h*32 + ntl*16 + l15)*DIM + kk*32 + g*8);
            }
            __builtin_amdgcn_s_setprio(1);
            #pragma unroll
            for (int ntl = 0; ntl < 2; ++ntl)
                #pragma unroll
                for (int qt = 0; qt < 4; ++qt) {
                    qacc[ntl][qt] = __builtin_amdgcn_mfma_f32_16x16x32_bf16(wq[ntl], xfr[qt], qacc[ntl][qt], 0, 0, 0);
                    kacc[ntl][qt] = __builtin_amdgcn_mfma_f32_16x16x32_bf16(wk[ntl], xfr[qt], kacc[ntl][qt], 0, 0, 0);
                }
            __builtin_amdgcn_s_setprio(0);
        }
        v4f bqv[2], bkv[2];
        #pragma unroll
        for (int ntl = 0; ntl < 2; ++ntl) {
            bqv[ntl] = *(const v4f*)&qb2[h*32 + ntl*16 + 4*g];
            bkv[ntl] = *(const v4f*)&qb2[DIM + h*32 + ntl*16 + 4*g];
        }
        #pragma unroll
        for (int qt = 0; qt < 4; ++qt) {
            union { v8s v; uint32_t d[4]; } uq, uk;
            uq.d[0] = pk2(qacc[0][qt][0]+bqv[0][0], qacc[0][qt][1]+bqv[0][1]);
            uq.d[1] = pk2(qacc[0][qt][2]+bqv[0][2], qacc[0][qt][3]+bqv[0][3]);
            uq.d[2] = pk2(qacc[1][qt][0]+bqv[1][0], qacc[1][qt][1]+bqv[1][1]);
            uq.d[3] = pk2(qacc[1][qt][2]+bqv[1][2], qacc[1][qt][3]+bqv[1][3]);
            uk.d[0] = pk2(kacc[0][qt][0]+bkv[0][0], kacc[0][qt][1]+bkv[0][1]);
            uk.d[1] = pk2(kacc[0][qt][2]+bkv[0][2], kacc[0][qt][3]+bkv[0][3]);
            uk.d[2] = pk2(kacc[1][qt][0]+bkv[1][0], kacc[1][qt][1]+bkv[1][1]);
            uk.d[3] = pk2(kacc[1][qt][2]+bkv[1][2], kacc[1][qt][3]+bkv[1][3]);
            qfr[qt] = uq.v;
            kfr[qt] = uk.v;
        }
    }

    // ---------- phase 2: attention, per-qt interleave (r11-proven) ----------
    uint32_t pd[2][4][4];
    const float* bt = biasT + h*4096;
    #pragma unroll
    for (int qt = 0; qt < 4; ++qt) {
        // issue bias loads first (independent) so they drain under the MFMAs
        v4f bb[4];
        #pragma unroll
        for (int kt = 0; kt < 4; ++kt)
            bb[kt] = *(const v4f*)&bt[(qt*16 + l15)*64 + kt*16 + 4*g];
        v4f sq[4];
        __builtin_amdgcn_s_setprio(1);
        #pragma unroll
        for (int kt = 0; kt < 4; ++kt)
            sq[kt] = __builtin_amdgcn_mfma_f32_16x16x32_bf16(kfr[kt], qfr[qt],
                         (v4f){0.f,0.f,0.f,0.f}, 0, 0, 0);
        __builtin_amdgcn_s_setprio(0);
        #pragma unroll
        for (int kt = 0; kt < 4; ++kt) sq[kt] += bb[kt];
        float mx = sq[0][0];
        #pragma unroll
        for (int kt = 0; kt < 4; ++kt)
            #pragma unroll
            for (int r = 0; r < 4; ++r) mx = fmaxf(mx, sq[kt][r]);
        mx = fmaxf(mx, __shfl_xor(mx, 16));
        mx = fmaxf(mx, __shfl_xor(mx, 32));
        float sum = 0.f;
        #pragma unroll
        for (int kt = 0; kt < 4; ++kt)
            #pragma unroll
            for (int r = 0; r < 4; ++r) {
                float e = __expf(sq[kt][r] - mx);
                sq[kt][r] = e; sum += e;
            }
        sum += __shfl_xor(sum, 16);
        sum += __shfl_xor(sum, 32);
        float inv = 1.f / sum;
        #pragma unroll
        for (int kt = 0; kt < 4; ++kt)
            #pragma unroll
            for (int r = 0; r < 4; ++r) sq[kt][r] *= inv;

        pd[0][qt][0] = pk2(sq[0][0], sq[0][1]);
        pd[0][qt][1] = pk2(sq[0][2], sq[0][3]);
        pd[0][qt][2] = pk2(sq[1][0], sq[1][1]);
        pd[0][qt][3] = pk2(sq[1][2], sq[1][3]);
        pd[1][qt][0] = pk2(sq[2][0], sq[2][1]);
        pd[1][qt][1] = pk2(sq[2][2], sq[2][3]);
        pd[1][qt][2] = pk2(sq[3][0], sq[3][1]);
        pd[1][qt][3] = pk2(sq[3][2], sq[3][3]);
    }

    // O^T = V^T P^T via register repacks; slot (g,j) <-> key 16*(2kk+(j>>2))+4g+(j&3)
    v4f oT[2][4];
    #pragma unroll
    for (int ntl = 0; ntl < 2; ++ntl)
        #pragma unroll
        for (int qt = 0; qt < 4; ++qt)
            oT[ntl][qt] = (v4f){0.f,0.f,0.f,0.f};
    #pragma unroll
    for (int kk = 0; kk < 2; ++kk) {
        v8s vfr[2];
        #pragma unroll
        for (int ntl = 0; ntl < 2; ++ntl) {
            union { v8s v; uint32_t d[4]; } uu;
            uu.d[0] = vd[2*kk  ][ntl][0]; uu.d[1] = vd[2*kk  ][ntl][1];
            uu.d[2] = vd[2*kk+1][ntl][0]; uu.d[3] = vd[2*kk+1][ntl][1];
            vfr[ntl] = uu.v;
        }
        __builtin_amdgcn_s_setprio(1);
        #pragma unroll
        for (int qt = 0; qt < 4; ++qt) {
            union { v8s v; uint32_t d[4]; } p;
            p.d[0] = pd[kk][qt][0]; p.d[1] = pd[kk][qt][1];
            p.d[2] = pd[kk][qt][2]; p.d[3] = pd[kk][qt][3];
            #pragma unroll
            for (int ntl = 0; ntl < 2; ++ntl)
                oT[ntl][qt] = __builtin_amdgcn_mfma_f32_16x16x32_bf16(vfr[ntl], p.v, oT[ntl][qt], 0, 0, 0);
        }
        __builtin_amdgcn_s_setprio(0);
    }

    // attn_out -> bO [64][AO_STR], b64 stores
    #pragma unroll
    for (int qt = 0; qt < 4; ++qt)
        #pragma unroll
        for (int ntl = 0; ntl < 2; ++ntl) {
            v2u o;
            o.x = pk2(oT[ntl][qt][0], oT[ntl][qt][1]);
            o.y = pk2(oT[ntl][qt][2], oT[ntl][qt][3]);
            *(v2u*)&bO[(qt*16 + l15)*AO_STR + h*32 + ntl*16 + 4*g] = o;
        }
    __syncthreads();   // B2: both AO tiles complete

    // ---------- phase 3: transposed proj GEMM + direct register scatter (r5-proven) ----------
    v4f pacc[2][4];
    #pragma unroll
    for (int ntl = 0; ntl < 2; ++ntl)
        #pragma unroll
        for (int qt = 0; qt < 4; ++qt)
            pacc[ntl][qt] = (v4f){0.f,0.f,0.f,0.f};
    #pragma unroll
    for (int kk = 0; kk < 6; ++kk) {
        v8s aofr[4];
        #pragma unroll
        for (int qt = 0; qt < 4; ++qt)
            aofr[qt] = *(const v8s*)&bO[(qt*16 + l15)*AO_STR + kk*32 + g*8];
        v8s pwfr[2];
        #pragma unroll
        for (int ntl = 0; ntl < 2; ++ntl)
            pwfr[ntl] = *(const v8s*)(pw + (size_t)(h*32 + ntl*16 + l15)*DIM + kk*32 + g*8);
        __builtin_amdgcn_s_setprio(1);
        #pragma unroll
        for (int ntl = 0; ntl < 2; ++ntl)
            #pragma unroll
            for (int qt = 0; qt < 4; ++qt)
                pacc[ntl][qt] = __builtin_amdgcn_mfma_f32_16x16x32_bf16(pwfr[ntl], aofr[qt], pacc[ntl][qt], 0, 0, 0);
        __builtin_amdgcn_s_setprio(0);
    }
    float pb[2][4];
    #pragma unroll
    for (int ntl = 0; ntl < 2; ++ntl) {
        v4f pbv = *(const v4f*)&proj_b[h*32 + ntl*16 + 4*g];
        #pragma unroll
        for (int r = 0; r < 4; ++r) pb[ntl][r] = pbv[r];
    }

    #pragma unroll
    for (int qt = 0; qt < 4; ++qt) {
        const int strow = 2*qt + (l15 >> 3);
        const int stcol = l15 & 7;
        int hh = wi*8 + strow + 4; if (hh >= IMG) hh -= IMG;
        int ww = wj*8 + stcol + 4; if (ww >= IMG) ww -= IMG;
        const size_t pix = (size_t)hh*IMG + ww;
        #pragma unroll
        for (int ntl = 0; ntl < 2; ++ntl)
            #pragma unroll
            for (int r = 0; r < 4; ++r) {
                const int c = h*32 + ntl*16 + 4*g + r;
                ob[(size_t)c*(IMG*IMG) + pix] = pacc[ntl][qt][r] + pb[ntl][r];
            }
    }
}

extern "C" void kernel_launch(void* const* d_in, const int* in_sizes, int n_in,
                              void* d_out, int out_size, void* d_ws, size_t ws_size,
                              hipStream_t stream) {
    const float* x        = (const float*)d_in[0];
    const float* qkv_w    = (const float*)d_in[1];
    const float* qkv_b    = (const float*)d_in[2];
    const float* proj_w   = (const float*)d_in[3];
    const float* proj_b   = (const float*)d_in[4];
    const float* rel_bias = (const float*)d_in[5];
    const int*   rel_idx  = (const int*)d_in[6];

    u16*   qw_bf  = (u16*)d_ws;                         // 221184 B
    u16*   pw_bf  = (u16*)((char*)d_ws + 221184);       //  73728 B
    float* qb2    = (float*)((char*)d_ws + 294912);     //   2304 B
    float* biasT  = (float*)((char*)d_ws + 297216);     //  98304 B
    float* out    = (float*)d_out;

    hipLaunchKernelGGL(prep_kernel, dim3(432), dim3(256), 0, stream,
                       qkv_w, qkv_b, proj_w, rel_bias, rel_idx, qw_bf, pw_bf, qb2, biasT);
    hipLaunchKernelGGL(winattn_kernel, dim3(NB * (NWIN*NWIN/2)), dim3(768), 0, stream,
                       x, proj_b, qw_bf, pw_bf, qb2, biasT, out);
}